// Round 11
// baseline (2725.687 us; speedup 1.0000x reference)
//
#include <hip/hip_runtime.h>
#include <hip/hip_bf16.h>

#define B_   8
#define T_   12
#define CIN  16
#define HD   96
#define COUT 8
#define CE   112
#define CD   104
#define HW   4096
#define WIMG 64

// LDS (bytes): tile 63,360 | gate-exchange 2 x 128 x 97 f32 = 99,328 -> 162,688
#define TILE_SH 31680
#define XG_F    12416            // 128 * 97 floats per exchange plane
#define LDS_BYTES (63360 + 2 * XG_F * 4)

typedef __hip_bfloat16 bf16;
typedef __attribute__((ext_vector_type(8))) short bf16x8;   // 8 bf16 (4 VGPRs)
typedef __attribute__((ext_vector_type(16))) float f32x16;  // MFMA 32x32 C/D
typedef __attribute__((ext_vector_type(4))) int i32x4;      // 16B payload

__device__ __forceinline__ float b2f(bf16 v) { return __bfloat162float(v); }
__device__ __forceinline__ float sigmf_(float x) { return 1.0f / (1.0f + __expf(-x)); }
__device__ __forceinline__ float tanhf_(float x) { return 2.0f / (1.0f + __expf(-2.0f * x)) - 1.0f; }

__device__ __forceinline__ float ldin(const void* p, long i, int f32) {
    return f32 ? ((const float*)p)[i] : b2f(((const bf16*)p)[i]);
}
__device__ __forceinline__ short f2bs(float v) {
    __hip_bfloat16 hv = __float2bfloat16(v);
    return *reinterpret_cast<short*>(&hv);
}

// MFMA with "+a": accumulators in AGPRs (register file headroom for 8 waves)
__device__ __forceinline__ void mfma_a(f32x16& acc, bf16x8 a, bf16x8 b) {
    asm("v_mfma_f32_32x32x16_bf16 %0, %1, %2, %0"
        : "+a"(acc) : "v"(a), "v"(b));
}

// 16B device-coherent (bypass) loads/stores for cross-block h exchange.
__device__ __forceinline__ i32x4 ldB16(const short* p) {
    i32x4 r;
    asm volatile("global_load_dwordx4 %0, %1, off sc0 sc1"
                 : "=v"(r) : "v"(p) : "memory");
    return r;
}
__device__ __forceinline__ void stB16(short* p, i32x4 v) {
    asm volatile("global_store_dwordx4 %0, %1, off sc0 sc1"
                 :: "v"(p), "v"(v) : "memory");
}
__device__ __forceinline__ void vm0() {
    asm volatile("s_waitcnt vmcnt(0)" ::: "memory");
}

// neighbor-pair progress sync (per-block counter on its own 64B line).
__device__ __forceinline__ void wait_prog(const int* p, int need) {
    while (__hip_atomic_load(p, __ATOMIC_RELAXED, __HIP_MEMORY_SCOPE_AGENT) < need)
        __builtin_amdgcn_s_sleep(1);
}

__device__ __forceinline__ int detect_flag(const void* w) {
    const unsigned short* u = (const unsigned short*)w;
    int bad = 0;
    for (int i = 0; i < 64; i++) {
        unsigned short v = u[i];
        unsigned e = (v >> 7) & 0xFF;
        if (!(v == 0 || (e >= 90 && e <= 128))) bad++;
    }
    return (bad > 8) ? 1 : 0;
}

// ---------------------------------------------------------------------------
// ONE fused setup kernel (unchanged layouts). Block ranges:
//   0-2: biases  3: b2+flag  4: prog zero  5-25: EW  26-214: WtA  215-230: K2A
// ---------------------------------------------------------------------------
__global__ void setup_k(
    const void* eWf, const void* ebf_, const void* eWi, const void* ebi_,
    const void* eWc, const void* ebc_, const void* eWo, const void* ebo_,
    const void* dKf, const void* dbf_, const void* dKi, const void* dbi_,
    const void* dKc, const void* dbc_, const void* dWo, const void* dbo_,
    const void* oK,  const void* obv,  const void* lW,  const void* lb,
    float* __restrict__ biases, float* __restrict__ b2,
    short* __restrict__ EW, short* __restrict__ WtA, short* __restrict__ K2A,
    int* __restrict__ flag, int* __restrict__ prog)
{
    const int f = detect_flag(eWf);
    const int bid = blockIdx.x, tid = threadIdx.x;

    if (bid < 3) {
        int idx = bid * 256 + tid;
        if (idx < 768) {
            const void* srcs[8] = {ebf_, ebi_, ebc_, ebo_, dbf_, dbi_, dbc_, dbo_};
            biases[idx] = ldin(srcs[idx / 96], idx % 96, f);
        }
        return;
    }
    if (bid == 3) {
        if (tid < COUT) {
            float a = ldin(lb, tid, f);
            for (int cd = 0; cd < CD; cd++)
                a = fmaf(ldin(obv, cd, f), ldin(lW, cd * COUT + tid, f), a);
            b2[tid] = a;
        }
        if (tid == 32) *flag = f;
        return;
    }
    if (bid == 4) {
        __hip_atomic_store(&prog[tid * 16], 0, __ATOMIC_RELAXED, __HIP_MEMORY_SCOPE_AGENT);
        return;
    }
    if (bid < 26) {                              // EW
        int lin = (bid - 5) * 256 + tid;
        if (lin >= 7 * 12 * 64) return;
        int lane = lin & 63;
        int rest = lin >> 6;
        int mt = rest % 12;
        int k0 = rest / 12;
        int m = mt * 32 + (lane & 31);
        int gate = m / 96, d = m % 96;
        int chb = k0 * 16 + (lane >> 5) * 8;
        const void* W = (gate == 0) ? eWf : (gate == 1) ? eWi : (gate == 2) ? eWc : eWo;
        #pragma unroll
        for (int j = 0; j < 8; j++)
            EW[(size_t)lin * 8 + j] = f2bs(ldin(W, (size_t)(chb + j) * HD + d, f));
        return;
    }
    if (bid < 215) {                             // WtA
        int lin = (bid - 26) * 256 + tid;
        if (lin >= 9 * 7 * 12 * 64) return;
        int lane = lin & 63;
        int rest = lin >> 6;
        int mt  = rest % 12;
        int k07 = rest / 12;
        int k0  = k07 % 7;
        int tap = k07 / 7;
        int m = mt * 32 + (lane & 31);
        int gate = m / 96, d = m % 96;
        int chb = k0 * 16 + (lane >> 5) * 8;
        #pragma unroll
        for (int j = 0; j < 8; j++) {
            int ch = chb + j;
            float v = 0.f;
            if (ch < 104) {
                long ki = ((long)d * CD + ch) * 9 + tap;
                if (gate == 0)      v = ldin(dKf, ki, f);
                else if (gate == 1) v = ldin(dKi, ki, f);
                else if (gate == 2) v = ldin(dKc, ki, f);
                else                v = (tap == 4) ? ldin(dWo, (long)ch * HD + d, f) : 0.f;
            }
            WtA[(size_t)lin * 8 + j] = f2bs(v);
        }
        return;
    }
    {                                            // K2A with combine inline
        int lin = (bid - 215) * 256 + tid;
        if (lin >= 9 * 7 * 64) return;
        int lane = lin & 63;
        int rest = lin >> 6;
        int k0 = rest % 7;
        int tap = rest / 7;
        int m = lane & 31;
        int kb = k0 * 16 + (lane >> 5) * 8;
        #pragma unroll 1
        for (int j = 0; j < 8; j++) {
            int c = kb + j - 8;
            float v = 0.f;
            if (m < 8 && c >= 0 && c < 96) {
                long i = (long)c * 9 + tap;
                for (int cd = 0; cd < CD; cd++)
                    v = fmaf(ldin(oK, (long)cd * (HD * 9) + i, f),
                             ldin(lW, (long)cd * COUT + m, f), v);
            }
            K2A[(size_t)lin * 8 + j] = f2bs(v);
        }
    }
}

// ---------------------------------------------------------------------------
// persistent kernel, 8-wave M-SPLIT blocks: 512 threads, grid 256 (1/CU).
// Group A (waves 0-3): f,i gate tiles + c-state + h-write, for px 0..127.
// Group B (waves 4-7): g,o gate tiles + out-head, SAME px; gate activations
// exchanged via stride-97 f32 LDS planes. 2 waves/SIMD -> stalls overlap.
// Per-accumulator MFMA order identical to prior rounds -> bit-identical out.
// ---------------------------------------------------------------------------
__global__ void __launch_bounds__(512, 2) net_k(
    const void* __restrict__ xe, const void* __restrict__ xd,
    short* __restrict__ hPA, short* __restrict__ hPB,
    void* __restrict__ out,
    const short* __restrict__ EW, const short* __restrict__ WtA,
    const short* __restrict__ K2A,
    const float* __restrict__ ebf, const float* __restrict__ ebi,
    const float* __restrict__ ebc, const float* __restrict__ ebo,
    const float* __restrict__ dbf, const float* __restrict__ dbi,
    const float* __restrict__ dbc, const float* __restrict__ dbo,
    const float* __restrict__ b2, const int* __restrict__ flag,
    int* __restrict__ prog)
{
    extern __shared__ short lds[];            // 162,688 B dynamic
    float* xg = (float*)(lds + TILE_SH);      // gate-exchange: tanh(g)
    float* xo = xg + XG_F;                    // gate-exchange: sigm(o)
    const int f32 = *flag;
    const int tid  = threadIdx.x;
    const int b    = blockIdx.x & 7;
    const int band = blockIdx.x >> 3;         // 0..31
    const int y0   = band * 2;
    const int pix0 = y0 * 64;
    const int wave = tid >> 6, lane = tid & 63;
    const int grp  = wave >> 2;               // 0 = f,i/c-owner  1 = g,o/out
    const int wv   = wave & 3;
    const int n = lane & 31, kj = lane >> 5;
    const int px = wv * 32 + n;               // block-local pixel 0..127
    const int pg = pix0 + px;                 // global pixel
    const i32x4 z4 = {0, 0, 0, 0};

    float cre[48];
    #pragma unroll
    for (int i = 0; i < 48; i++) cre[i] = 0.f;

    // ================= encoder phase =====
    #pragma unroll 1
    for (int t = 0; t < T_; t++) {
        // x staging: 512 items, one per thread
        {
            int ch = tid & 15, q = tid >> 4;
            size_t base = ((size_t)(b * T_ + t) * CIN + ch) * HW + pix0 + q * 4;
            short v0, v1, v2, v3;
            if (f32) {
                float4 f = *(const float4*)((const float*)xe + base);
                v0 = f2bs(f.x); v1 = f2bs(f.y); v2 = f2bs(f.z); v3 = f2bs(f.w);
            } else {
                short4 sv = *(const short4*)((const short*)xe + base);
                v0 = sv.x; v1 = sv.y; v2 = sv.z; v3 = sv.w;
            }
            int sb = q * 4;
            lds[(sb + 0) * 120 + ch] = v0;
            lds[(sb + 1) * 120 + ch] = v1;
            lds[(sb + 2) * 120 + ch] = v2;
            lds[(sb + 3) * 120 + ch] = v3;
        }
        __syncthreads();

        f32x16 acc[6];
        #pragma unroll
        for (int m = 0; m < 6; m++)
            #pragma unroll
            for (int r = 0; r < 16; r++) acc[m][r] = 0.f;

        const short* rec = &lds[px * 120];
        const int mt0 = grp * 6;
        if (t == 0) {
            bf16x8 cB = *(const bf16x8*)(rec + kj * 8);
            #pragma unroll
            for (int m = 0; m < 6; m++)
                mfma_a(acc[m], *(const bf16x8*)(EW + (size_t)(mt0 + m) * 512 + lane * 8), cB);
        } else {
            bf16x8 cA[6], cB;
            cB = *(const bf16x8*)(rec + kj * 8);
            #pragma unroll
            for (int m = 0; m < 6; m++)
                cA[m] = *(const bf16x8*)(EW + (size_t)(mt0 + m) * 512 + lane * 8);
            #pragma unroll
            for (int k0 = 0; k0 < 7; k0++) {
                bf16x8 nA[6], nB;
                if (k0 < 6) {
                    nB = *(const bf16x8*)(rec + (k0 + 1) * 16 + kj * 8);
                    #pragma unroll
                    for (int m = 0; m < 6; m++)
                        nA[m] = *(const bf16x8*)(EW + (size_t)((k0 + 1) * 12 + mt0 + m) * 512 + lane * 8);
                }
                #pragma unroll
                for (int m = 0; m < 6; m++) mfma_a(acc[m], cA[m], cB);
                if (k0 < 6) {
                    #pragma unroll
                    for (int m = 0; m < 6; m++) cA[m] = nA[m];
                    cB = nB;
                }
            }
        }
        __syncthreads();

        // B publishes gate activations
        if (grp == 1) {
            #pragma unroll
            for (int dt = 0; dt < 3; dt++)
                #pragma unroll
                for (int r = 0; r < 16; r++) {
                    int row = (r & 3) + 8 * (r >> 2) + 4 * kj;
                    int d = dt * 32 + row;
                    xg[px * 97 + d] = tanhf_(acc[dt][r]     + ebc[d]);
                    xo[px * 97 + d] = sigmf_(acc[3 + dt][r] + ebo[d]);
                }
        }
        __syncthreads();
        // A: LSTM pointwise, c in regs, h -> own LDS rec (+16 offset)
        if (grp == 0) {
            #pragma unroll
            for (int dt = 0; dt < 3; dt++)
                #pragma unroll
                for (int r = 0; r < 16; r++) {
                    int row = (r & 3) + 8 * (r >> 2) + 4 * kj;
                    int d = dt * 32 + row;
                    float fg = sigmf_(acc[dt][r]     + ebf[d]);
                    float ig = sigmf_(acc[3 + dt][r] + ebi[d]);
                    int ci = dt * 16 + r;
                    float cn = fmaf(cre[ci], fg, ig * xg[px * 97 + d]);
                    cre[ci] = cn;
                    lds[px * 120 + 16 + d] = f2bs(tanhf_(cn) * xo[px * 97 + d]);
                }
        }
        __syncthreads();
        if (t == T_ - 1) {
            // publish final enc h: 128 recs x 12 parts x 16B = full 96 ch
            #pragma unroll 1
            for (int c = tid; c < 1536; c += 512) {
                int rec2 = c / 12, part = c - (c / 12) * 12;
                stB16(hPA + ((size_t)b * HW + pix0 + rec2) * 96 + part * 8,
                      *(const i32x4*)(&lds[rec2 * 120 + 16 + part * 8]));
            }
        }
    }
    vm0();
    __syncthreads();
    if (tid == 0)
        __hip_atomic_store(&prog[blockIdx.x * 16], 1, __ATOMIC_RELAXED, __HIP_MEMORY_SCOPE_AGENT);

    // ================= decoder phase =====
    #pragma unroll 1
    for (int tt = 0; tt <= T_; tt++) {
        short* hR  = (tt & 1) ? hPB : hPA;    // h_{tt-1}
        short* hWr = (tt & 1) ? hPA : hPB;    // h_tt

        if (tt == 0) {
            // zero pass: edge slots + ch pads
            #pragma unroll 1
            for (int i = tid; i < 648; i += 512) {
                int addr_sh;
                if (i < 120) {
                    int r = i / 30, rem = i % 30;
                    int s = (rem / 15) * 65;
                    addr_sh = (r * 66 + s) * 120 + (rem % 15) * 8;
                } else {
                    int z = i - 120;
                    addr_sh = (z >> 1) * 120 + 104 + (z & 1) * 8;
                }
                *(i32x4*)(&lds[addr_sh]) = z4;
            }
        }
        // x staging: 512 items (skip on final out-only pass)
        if (tt < T_) {
            int ch = tid & 7, q = (tid >> 3) & 15, r = tid >> 7;
            int y = y0 - 1 + r;
            short v0 = 0, v1 = 0, v2 = 0, v3 = 0;
            if ((unsigned)y < 64u) {
                size_t base = ((size_t)(b * T_ + tt) * COUT + ch) * HW + y * 64 + q * 4;
                if (f32) {
                    float4 f = *(const float4*)((const float*)xd + base);
                    v0 = f2bs(f.x); v1 = f2bs(f.y); v2 = f2bs(f.z); v3 = f2bs(f.w);
                } else {
                    short4 sv = *(const short4*)((const short*)xd + base);
                    v0 = sv.x; v1 = sv.y; v2 = sv.z; v3 = sv.w;
                }
            }
            int sb = r * 66 + 1 + q * 4;
            lds[(sb + 0) * 120 + ch] = v0;
            lds[(sb + 1) * 120 + ch] = v1;
            lds[(sb + 2) * 120 + ch] = v2;
            lds[(sb + 3) * 120 + ch] = v3;
        }

        // neighbor sync: need h_{tt-1} of bands band+-1 published (prog>=tt+1)
        if (tid < 2) {
            int nb = band + (tid ? 1 : -1);
            if ((unsigned)nb < 32u)
                wait_prog(prog + (((nb << 3) | b) << 4), tt + 1);
        }
        __syncthreads();

        if (tt == 0) {
            // full h staging: 3072 chunks, 6 per thread
            i32x4 tmp[6]; int ss2[6], jj2[6];
            #pragma unroll
            for (int i = 0; i < 6; i++) {
                int c2 = tid + i * 512;
                int s = c2 / 12, j = c2 - s * 12;
                ss2[i] = s; jj2[i] = j;
                int y = y0 - 1 + (s >> 6);
                if ((unsigned)y < 64u)
                    tmp[i] = ldB16(hR + ((size_t)b * HW + (size_t)y * 64 + (s & 63)) * 96 + j * 8);
                else tmp[i] = z4;
            }
            vm0();
            #pragma unroll
            for (int i = 0; i < 6; i++) {
                int s = ss2[i];
                *(i32x4*)(&lds[((s >> 6) * 66 + 1 + (s & 63)) * 120 + 8 + jj2[i] * 8]) = tmp[i];
            }
        } else {
            // halo staging: rows y0-1 (slot 0) and y0+2 (slot 3); 3 per thread
            i32x4 tmp[3]; int ss2[3], jj2[3];
            #pragma unroll
            for (int i = 0; i < 3; i++) {
                int c2 = tid + i * 512;           // 0..1535
                int s = c2 / 12, j = c2 - s * 12; // s 0..127
                int hi = s >> 6;
                int y = hi ? (y0 + 2) : (y0 - 1);
                ss2[i] = hi * 3 * 66 + 1 + (s & 63);
                jj2[i] = j;
                if ((unsigned)y < 64u)
                    tmp[i] = ldB16(hR + ((size_t)b * HW + (size_t)y * 64 + (s & 63)) * 96 + j * 8);
                else tmp[i] = z4;
            }
            vm0();
            #pragma unroll
            for (int i = 0; i < 3; i++)
                *(i32x4*)(&lds[ss2[i] * 120 + 8 + jj2[i] * 8]) = tmp[i];
        }
        __syncthreads();

        const int rw = 1 + (wv >> 1);
        const int x0 = (wv & 1) * 32;

        f32x16 aF[6], aG[3], aOc[3], aOut;
        if (grp == 0) {
            #pragma unroll
            for (int m = 0; m < 6; m++)
                #pragma unroll
                for (int r = 0; r < 16; r++) aF[m][r] = 0.f;
        } else {
            #pragma unroll
            for (int m = 0; m < 3; m++)
                #pragma unroll
                for (int r = 0; r < 16; r++) { aG[m][r] = 0.f; aOc[m][r] = 0.f; }
            #pragma unroll
            for (int r = 0; r < 16; r++) aOut[r] = 0.f;
        }

        // ---- MFMA phase (no barriers inside; groups diverge at wave level)
        if (grp == 0 && tt < T_) {
            // f,i tiles (mt 0-5), taps 0-8 x k0 0-6, 1-deep prefetch
            bf16x8 cA[6], cB;
            cB = *(const bf16x8*)(&lds[((rw - 1) * 66 + x0 + n) * 120] + kj * 8);
            #pragma unroll
            for (int m = 0; m < 6; m++)
                cA[m] = *(const bf16x8*)(WtA + (size_t)m * 512 + lane * 8);
            #pragma unroll 1
            for (int u = 0; u < 63; u++) {
                int un = (u < 62) ? u + 1 : 62;
                int tapn = un / 7, k0n = un - tapn * 7;
                int dyn_ = tapn / 3 - 1, dxn = tapn - (tapn / 3) * 3 - 1;
                bf16x8 nA[6], nB;
                nB = *(const bf16x8*)(&lds[((rw + dyn_) * 66 + 1 + x0 + n + dxn) * 120]
                                      + k0n * 16 + kj * 8);
                #pragma unroll
                for (int m = 0; m < 6; m++)
                    nA[m] = *(const bf16x8*)(WtA + ((size_t)un * 12 + m) * 512 + lane * 8);
                #pragma unroll
                for (int m = 0; m < 6; m++) mfma_a(aF[m], cA[m], cB);
                #pragma unroll
                for (int m = 0; m < 6; m++) cA[m] = nA[m];
                cB = nB;
            }
        }
        if (grp == 1) {
            // g tiles (mt 6-8) + out head, taps 0-8 x k0 0-6
            bf16x8 cG[3], cK, cB;
            cB = *(const bf16x8*)(&lds[((rw - 1) * 66 + x0 + n) * 120] + kj * 8);
            #pragma unroll
            for (int m = 0; m < 3; m++)
                cG[m] = *(const bf16x8*)(WtA + (size_t)(6 + m) * 512 + lane * 8);
            cK = *(const bf16x8*)(K2A + lane * 8);
            #pragma unroll 1
            for (int u = 0; u < 63; u++) {
                int un = (u < 62) ? u + 1 : 62;
                int tapn = un / 7, k0n = un - tapn * 7;
                int dyn_ = tapn / 3 - 1, dxn = tapn - (tapn / 3) * 3 - 1;
                bf16x8 nG[3], nK, nB;
                nB = *(const bf16x8*)(&lds[((rw + dyn_) * 66 + 1 + x0 + n + dxn) * 120]
                                      + k0n * 16 + kj * 8);
                #pragma unroll
                for (int m = 0; m < 3; m++)
                    nG[m] = *(const bf16x8*)(WtA + ((size_t)un * 12 + 6 + m) * 512 + lane * 8);
                nK = *(const bf16x8*)(K2A + (size_t)un * 512 + lane * 8);
                if (tt < T_) {
                    #pragma unroll
                    for (int m = 0; m < 3; m++) mfma_a(aG[m], cG[m], cB);
                }
                if (tt > 0) mfma_a(aOut, cK, cB);
                #pragma unroll
                for (int m = 0; m < 3; m++) cG[m] = nG[m];
                cK = nK; cB = nB;
            }
            // o tiles (mt 9-11): center tap only
            if (tt < T_) {
                const short* recc = &lds[(rw * 66 + 1 + x0 + n) * 120];
                bf16x8 cO[3], cB2 = *(const bf16x8*)(recc + kj * 8);
                #pragma unroll
                for (int m = 0; m < 3; m++)
                    cO[m] = *(const bf16x8*)(WtA + ((size_t)28 * 12 + 9 + m) * 512 + lane * 8);
                #pragma unroll
                for (int k0 = 0; k0 < 7; k0++) {
                    bf16x8 nO[3], nB2;
                    if (k0 < 6) {
                        nB2 = *(const bf16x8*)(recc + (k0 + 1) * 16 + kj * 8);
                        #pragma unroll
                        for (int m = 0; m < 3; m++)
                            nO[m] = *(const bf16x8*)(WtA + ((size_t)(29 + k0) * 12 + 9 + m) * 512 + lane * 8);
                    }
                    #pragma unroll
                    for (int m = 0; m < 3; m++) mfma_a(aOc[m], cO[m], cB2);
                    if (k0 < 6) {
                        #pragma unroll
                        for (int m = 0; m < 3; m++) cO[m] = nO[m];
                        cB2 = nB2;
                    }
                }
            }
        }
        __syncthreads();

        // B publishes gate activations
        if (grp == 1 && tt < T_) {
            #pragma unroll
            for (int dt = 0; dt < 3; dt++)
                #pragma unroll
                for (int r = 0; r < 16; r++) {
                    int row = (r & 3) + 8 * (r >> 2) + 4 * kj;
                    int d = dt * 32 + row;
                    xg[px * 97 + d] = tanhf_(aG[dt][r]  + dbc[d]);
                    xo[px * 97 + d] = sigmf_(aOc[dt][r] + dbo[d]);
                }
        }
        __syncthreads();

        // B: fused out store for step tt-1 || A: LSTM pointwise + h-write
        if (grp == 1 && tt > 0) {
            #pragma unroll
            for (int r = 0; r < 4; r++) {
                int o = r + 4 * kj;
                float v = aOut[r] + b2[o];
                size_t oadr = ((size_t)(b * T_ + (tt - 1)) * COUT + o) * HW + pg;
                if (f32) ((float*)out)[oadr] = v;
                else     ((bf16*)out)[oadr] = __float2bfloat16(v);
            }
        }
        if (grp == 0 && tt < T_) {
            #pragma unroll
            for (int dt = 0; dt < 3; dt++)
                #pragma unroll
                for (int r = 0; r < 16; r++) {
                    int row = (r & 3) + 8 * (r >> 2) + 4 * kj;
                    int d = dt * 32 + row;
                    float fg = sigmf_(aF[dt][r]     + dbf[d]);
                    float ig = sigmf_(aF[3 + dt][r] + dbi[d]);
                    int ci = dt * 16 + r;
                    float cn = fmaf(cre[ci], fg, ig * xg[px * 97 + d]);
                    cre[ci] = cn;
                    lds[((1 + (px >> 6)) * 66 + 1 + (px & 63)) * 120 + 8 + d]
                        = f2bs(tanhf_(cn) * xo[px * 97 + d]);
                }
        }
        __syncthreads();

        if (tt < T_) {
            // publish own 2 rows: 128 recs x 12 parts x 16B = full 96 ch
            #pragma unroll 1
            for (int c = tid; c < 1536; c += 512) {
                int rec2 = c / 12, part = c - (c / 12) * 12;
                stB16(hWr + ((size_t)b * HW + pix0 + rec2) * 96 + part * 8,
                      *(const i32x4*)(&lds[((1 + (rec2 >> 6)) * 66 + 1 + (rec2 & 63)) * 120
                                           + 8 + part * 8]));
            }
            vm0();
            __syncthreads();
            if (tid == 0)
                __hip_atomic_store(&prog[blockIdx.x * 16], tt + 2,
                                   __ATOMIC_RELAXED, __HIP_MEMORY_SCOPE_AGENT);
        }
    }
}

// ---------------------------------------------------------------------------
extern "C" void kernel_launch(void* const* d_in, const int* in_sizes, int n_in,
                              void* d_out, int out_size, void* d_ws, size_t ws_size,
                              hipStream_t stream)
{
    const void* enc_in = d_in[0];
    const void* dec_in = d_in[1];
    const void* eWf = d_in[2];  const void* ebf_ = d_in[3];
    const void* eWi = d_in[4];  const void* ebi_ = d_in[5];
    const void* eWc = d_in[6];  const void* ebc_ = d_in[7];
    const void* eWo = d_in[8];  const void* ebo_ = d_in[9];
    const void* dKf = d_in[10]; const void* dbf_ = d_in[11];
    const void* dKi = d_in[12]; const void* dbi_ = d_in[13];
    const void* dKc = d_in[14]; const void* dbc_ = d_in[15];
    const void* dWo = d_in[16]; const void* dbo_ = d_in[17];
    const void* oK  = d_in[18]; const void* obv = d_in[19];
    const void* lW  = d_in[20]; const void* lb  = d_in[21];

    int* flag = (int*)d_ws;
    int* prog = (int*)d_ws + 16;             // 256 slots x 16 ints (64B stride)
    float* ws = (float*)d_ws + 16 + 4096;

    const int S = B_ * HD * HW;              // 3,145,728 state elems
    short* hPA = (short*)ws;                 // S shorts (pixel-major h)
    short* hPB = (short*)(ws + S / 2);       // S shorts
    float* biases = ws + S;                  // 8 x 96 fp32
    float* b2   = biases + 768;              // 16
    short* WtA  = (short*)(b2 + 16);                  // 387,072 shorts
    short* EW   = (short*)(b2 + 16 + 193536);         // 43,008 shorts
    short* K2A  = (short*)(b2 + 16 + 193536 + 21504); // 32,256 shorts

    hipFuncSetAttribute(reinterpret_cast<const void*>(net_k),
                        hipFuncAttributeMaxDynamicSharedMemorySize, LDS_BYTES);

    setup_k<<<dim3(231), dim3(256), 0, stream>>>(
        eWf, ebf_, eWi, ebi_, eWc, ebc_, eWo, ebo_,
        dKf, dbf_, dKi, dbi_, dKc, dbc_, dWo, dbo_,
        oK, obv, lW, lb,
        biases, b2, EW, WtA, K2A, flag, prog);

    net_k<<<dim3(256), dim3(512), LDS_BYTES, stream>>>(
        enc_in, dec_in, hPA, hPB, d_out,
        EW, WtA, K2A,
        biases + 0, biases + 96, biases + 192, biases + 288,
        biases + 384, biases + 480, biases + 576, biases + 672,
        b2, flag, prog);
}

// Round 12
// 2199.862 us; speedup vs baseline: 1.2390x; 1.2390x over previous
//
#include <hip/hip_runtime.h>
#include <hip/hip_bf16.h>

#define B_   8
#define T_   12
#define CIN  16
#define HD   96
#define COUT 8
#define CE   112
#define CD   104
#define HW   4096
#define WIMG 64

// LDS (bytes): tile 63,360 | gate-exchange 2 x 128 x 97 f32 = 99,328 -> 162,688
#define TILE_SH 31680
#define XG_F    12416            // 128 * 97 floats per exchange plane
#define LDS_BYTES (63360 + 2 * XG_F * 4)

typedef __hip_bfloat16 bf16;
typedef __attribute__((ext_vector_type(8))) short bf16x8;   // 8 bf16 (4 VGPRs)
typedef __attribute__((ext_vector_type(16))) float f32x16;  // MFMA 32x32 C/D
typedef __attribute__((ext_vector_type(4))) int i32x4;      // 16B payload

__device__ __forceinline__ float b2f(bf16 v) { return __bfloat162float(v); }
__device__ __forceinline__ float sigmf_(float x) { return 1.0f / (1.0f + __expf(-x)); }
__device__ __forceinline__ float tanhf_(float x) { return 2.0f / (1.0f + __expf(-2.0f * x)) - 1.0f; }

__device__ __forceinline__ float ldin(const void* p, long i, int f32) {
    return f32 ? ((const float*)p)[i] : b2f(((const bf16*)p)[i]);
}
__device__ __forceinline__ short f2bs(float v) {
    __hip_bfloat16 hv = __float2bfloat16(v);
    return *reinterpret_cast<short*>(&hv);
}

// MFMA with "+a": accumulators in AGPRs
__device__ __forceinline__ void mfma_a(f32x16& acc, bf16x8 a, bf16x8 b) {
    asm("v_mfma_f32_32x32x16_bf16 %0, %1, %2, %0"
        : "+a"(acc) : "v"(a), "v"(b));
}

// 16B device-coherent (bypass) loads/stores for cross-block h exchange.
__device__ __forceinline__ i32x4 ldB16(const short* p) {
    i32x4 r;
    asm volatile("global_load_dwordx4 %0, %1, off sc0 sc1"
                 : "=v"(r) : "v"(p) : "memory");
    return r;
}
__device__ __forceinline__ void stB16(short* p, i32x4 v) {
    asm volatile("global_store_dwordx4 %0, %1, off sc0 sc1"
                 :: "v"(p), "v"(v) : "memory");
}
__device__ __forceinline__ void vm0() {
    asm volatile("s_waitcnt vmcnt(0)" ::: "memory");
}

// neighbor-pair progress sync (per-block counter on its own 64B line).
__device__ __forceinline__ void wait_prog(const int* p, int need) {
    while (__hip_atomic_load(p, __ATOMIC_RELAXED, __HIP_MEMORY_SCOPE_AGENT) < need)
        __builtin_amdgcn_s_sleep(1);
}

__device__ __forceinline__ int detect_flag(const void* w) {
    const unsigned short* u = (const unsigned short*)w;
    int bad = 0;
    for (int i = 0; i < 64; i++) {
        unsigned short v = u[i];
        unsigned e = (v >> 7) & 0xFF;
        if (!(v == 0 || (e >= 90 && e <= 128))) bad++;
    }
    return (bad > 8) ? 1 : 0;
}

// ---------------------------------------------------------------------------
// ONE fused setup kernel (unchanged layouts). Block ranges:
//   0-2: biases  3: b2+flag  4: prog zero  5-25: EW  26-214: WtA  215-230: K2A
// ---------------------------------------------------------------------------
__global__ void setup_k(
    const void* eWf, const void* ebf_, const void* eWi, const void* ebi_,
    const void* eWc, const void* ebc_, const void* eWo, const void* ebo_,
    const void* dKf, const void* dbf_, const void* dKi, const void* dbi_,
    const void* dKc, const void* dbc_, const void* dWo, const void* dbo_,
    const void* oK,  const void* obv,  const void* lW,  const void* lb,
    float* __restrict__ biases, float* __restrict__ b2,
    short* __restrict__ EW, short* __restrict__ WtA, short* __restrict__ K2A,
    int* __restrict__ flag, int* __restrict__ prog)
{
    const int f = detect_flag(eWf);
    const int bid = blockIdx.x, tid = threadIdx.x;

    if (bid < 3) {
        int idx = bid * 256 + tid;
        if (idx < 768) {
            const void* srcs[8] = {ebf_, ebi_, ebc_, ebo_, dbf_, dbi_, dbc_, dbo_};
            biases[idx] = ldin(srcs[idx / 96], idx % 96, f);
        }
        return;
    }
    if (bid == 3) {
        if (tid < COUT) {
            float a = ldin(lb, tid, f);
            for (int cd = 0; cd < CD; cd++)
                a = fmaf(ldin(obv, cd, f), ldin(lW, cd * COUT + tid, f), a);
            b2[tid] = a;
        }
        if (tid == 32) *flag = f;
        return;
    }
    if (bid == 4) {
        __hip_atomic_store(&prog[tid * 16], 0, __ATOMIC_RELAXED, __HIP_MEMORY_SCOPE_AGENT);
        return;
    }
    if (bid < 26) {                              // EW
        int lin = (bid - 5) * 256 + tid;
        if (lin >= 7 * 12 * 64) return;
        int lane = lin & 63;
        int rest = lin >> 6;
        int mt = rest % 12;
        int k0 = rest / 12;
        int m = mt * 32 + (lane & 31);
        int gate = m / 96, d = m % 96;
        int chb = k0 * 16 + (lane >> 5) * 8;
        const void* W = (gate == 0) ? eWf : (gate == 1) ? eWi : (gate == 2) ? eWc : eWo;
        #pragma unroll
        for (int j = 0; j < 8; j++)
            EW[(size_t)lin * 8 + j] = f2bs(ldin(W, (size_t)(chb + j) * HD + d, f));
        return;
    }
    if (bid < 215) {                             // WtA
        int lin = (bid - 26) * 256 + tid;
        if (lin >= 9 * 7 * 12 * 64) return;
        int lane = lin & 63;
        int rest = lin >> 6;
        int mt  = rest % 12;
        int k07 = rest / 12;
        int k0  = k07 % 7;
        int tap = k07 / 7;
        int m = mt * 32 + (lane & 31);
        int gate = m / 96, d = m % 96;
        int chb = k0 * 16 + (lane >> 5) * 8;
        #pragma unroll
        for (int j = 0; j < 8; j++) {
            int ch = chb + j;
            float v = 0.f;
            if (ch < 104) {
                long ki = ((long)d * CD + ch) * 9 + tap;
                if (gate == 0)      v = ldin(dKf, ki, f);
                else if (gate == 1) v = ldin(dKi, ki, f);
                else if (gate == 2) v = ldin(dKc, ki, f);
                else                v = (tap == 4) ? ldin(dWo, (long)ch * HD + d, f) : 0.f;
            }
            WtA[(size_t)lin * 8 + j] = f2bs(v);
        }
        return;
    }
    {                                            // K2A with combine inline
        int lin = (bid - 215) * 256 + tid;
        if (lin >= 9 * 7 * 64) return;
        int lane = lin & 63;
        int rest = lin >> 6;
        int k0 = rest % 7;
        int tap = rest / 7;
        int m = lane & 31;
        int kb = k0 * 16 + (lane >> 5) * 8;
        #pragma unroll 1
        for (int j = 0; j < 8; j++) {
            int c = kb + j - 8;
            float v = 0.f;
            if (m < 8 && c >= 0 && c < 96) {
                long i = (long)c * 9 + tap;
                for (int cd = 0; cd < CD; cd++)
                    v = fmaf(ldin(oK, (long)cd * (HD * 9) + i, f),
                             ldin(lW, (long)cd * COUT + m, f), v);
            }
            K2A[(size_t)lin * 8 + j] = f2bs(v);
        }
    }
}

// ---------------------------------------------------------------------------
// persistent kernel, 8-wave M-SPLIT blocks: 512 threads, grid 256 (1/CU).
// Group A (waves 0-3): f,i gate tiles + c-state + h-write, for px 0..127.
// Group B (waves 4-7): g,o gate tiles + out-head, SAME px; exchange via LDS.
// Decoder accumulators are a UNIONED f32x16 A[7] (grp0: f,i = A[0..5];
// grp1: g = A[0..2], o = A[3..5], out = A[6]) -- 112 acc regs instead of
// 208, which is what un-spills the R11 build (VGPR cap 128 + 4.6 GB scratch).
// Per-accumulator MFMA order identical to prior rounds -> bit-identical out.
// ---------------------------------------------------------------------------
__global__ void __launch_bounds__(512, 2) net_k(
    const void* __restrict__ xe, const void* __restrict__ xd,
    short* __restrict__ hPA, short* __restrict__ hPB,
    void* __restrict__ out,
    const short* __restrict__ EW, const short* __restrict__ WtA,
    const short* __restrict__ K2A,
    const float* __restrict__ ebf, const float* __restrict__ ebi,
    const float* __restrict__ ebc, const float* __restrict__ ebo,
    const float* __restrict__ dbf, const float* __restrict__ dbi,
    const float* __restrict__ dbc, const float* __restrict__ dbo,
    const float* __restrict__ b2, const int* __restrict__ flag,
    int* __restrict__ prog)
{
    extern __shared__ short lds[];            // 162,688 B dynamic
    float* xg = (float*)(lds + TILE_SH);      // gate-exchange: tanh(g)
    float* xo = xg + XG_F;                    // gate-exchange: sigm(o)
    const int f32 = *flag;
    const int tid  = threadIdx.x;
    const int b    = blockIdx.x & 7;
    const int band = blockIdx.x >> 3;         // 0..31
    const int y0   = band * 2;
    const int pix0 = y0 * 64;
    const int wave = tid >> 6, lane = tid & 63;
    const int grp  = wave >> 2;               // 0 = f,i/c-owner  1 = g,o/out
    const int wv   = wave & 3;
    const int n = lane & 31, kj = lane >> 5;
    const int px = wv * 32 + n;               // block-local pixel 0..127
    const int pg = pix0 + px;                 // global pixel
    const i32x4 z4 = {0, 0, 0, 0};

    float cre[48];
    #pragma unroll
    for (int i = 0; i < 48; i++) cre[i] = 0.f;

    // ================= encoder phase =====
    #pragma unroll 1
    for (int t = 0; t < T_; t++) {
        // x staging: 512 items, one per thread
        {
            int ch = tid & 15, q = tid >> 4;
            size_t base = ((size_t)(b * T_ + t) * CIN + ch) * HW + pix0 + q * 4;
            short v0, v1, v2, v3;
            if (f32) {
                float4 f = *(const float4*)((const float*)xe + base);
                v0 = f2bs(f.x); v1 = f2bs(f.y); v2 = f2bs(f.z); v3 = f2bs(f.w);
            } else {
                short4 sv = *(const short4*)((const short*)xe + base);
                v0 = sv.x; v1 = sv.y; v2 = sv.z; v3 = sv.w;
            }
            int sb = q * 4;
            lds[(sb + 0) * 120 + ch] = v0;
            lds[(sb + 1) * 120 + ch] = v1;
            lds[(sb + 2) * 120 + ch] = v2;
            lds[(sb + 3) * 120 + ch] = v3;
        }
        __syncthreads();

        f32x16 acc[6];
        #pragma unroll
        for (int m = 0; m < 6; m++)
            #pragma unroll
            for (int r = 0; r < 16; r++) acc[m][r] = 0.f;

        const short* rec = &lds[px * 120];
        const int mt0 = grp * 6;
        if (t == 0) {
            bf16x8 cB = *(const bf16x8*)(rec + kj * 8);
            #pragma unroll
            for (int m = 0; m < 6; m++)
                mfma_a(acc[m], *(const bf16x8*)(EW + (size_t)(mt0 + m) * 512 + lane * 8), cB);
        } else {
            bf16x8 cA[6], cB;
            cB = *(const bf16x8*)(rec + kj * 8);
            #pragma unroll
            for (int m = 0; m < 6; m++)
                cA[m] = *(const bf16x8*)(EW + (size_t)(mt0 + m) * 512 + lane * 8);
            #pragma unroll
            for (int k0 = 0; k0 < 7; k0++) {
                bf16x8 nA[6], nB;
                if (k0 < 6) {
                    nB = *(const bf16x8*)(rec + (k0 + 1) * 16 + kj * 8);
                    #pragma unroll
                    for (int m = 0; m < 6; m++)
                        nA[m] = *(const bf16x8*)(EW + (size_t)((k0 + 1) * 12 + mt0 + m) * 512 + lane * 8);
                }
                #pragma unroll
                for (int m = 0; m < 6; m++) mfma_a(acc[m], cA[m], cB);
                if (k0 < 6) {
                    #pragma unroll
                    for (int m = 0; m < 6; m++) cA[m] = nA[m];
                    cB = nB;
                }
            }
        }
        __syncthreads();

        // B publishes gate activations
        if (grp == 1) {
            #pragma unroll
            for (int dt = 0; dt < 3; dt++)
                #pragma unroll
                for (int r = 0; r < 16; r++) {
                    int row = (r & 3) + 8 * (r >> 2) + 4 * kj;
                    int d = dt * 32 + row;
                    xg[px * 97 + d] = tanhf_(acc[dt][r]     + ebc[d]);
                    xo[px * 97 + d] = sigmf_(acc[3 + dt][r] + ebo[d]);
                }
        }
        __syncthreads();
        // A: LSTM pointwise, c in regs, h -> own LDS rec (+16 offset)
        if (grp == 0) {
            #pragma unroll
            for (int dt = 0; dt < 3; dt++)
                #pragma unroll
                for (int r = 0; r < 16; r++) {
                    int row = (r & 3) + 8 * (r >> 2) + 4 * kj;
                    int d = dt * 32 + row;
                    float fg = sigmf_(acc[dt][r]     + ebf[d]);
                    float ig = sigmf_(acc[3 + dt][r] + ebi[d]);
                    int ci = dt * 16 + r;
                    float cn = fmaf(cre[ci], fg, ig * xg[px * 97 + d]);
                    cre[ci] = cn;
                    lds[px * 120 + 16 + d] = f2bs(tanhf_(cn) * xo[px * 97 + d]);
                }
        }
        __syncthreads();
        if (t == T_ - 1) {
            // publish final enc h: 128 recs x 12 parts x 16B = full 96 ch
            #pragma unroll 1
            for (int c = tid; c < 1536; c += 512) {
                int rec2 = c / 12, part = c - (c / 12) * 12;
                stB16(hPA + ((size_t)b * HW + pix0 + rec2) * 96 + part * 8,
                      *(const i32x4*)(&lds[rec2 * 120 + 16 + part * 8]));
            }
        }
    }
    vm0();
    __syncthreads();
    if (tid == 0)
        __hip_atomic_store(&prog[blockIdx.x * 16], 1, __ATOMIC_RELAXED, __HIP_MEMORY_SCOPE_AGENT);

    // ================= decoder phase =====
    #pragma unroll 1
    for (int tt = 0; tt <= T_; tt++) {
        short* hR  = (tt & 1) ? hPB : hPA;    // h_{tt-1}
        short* hWr = (tt & 1) ? hPA : hPB;    // h_tt

        if (tt == 0) {
            // zero pass: edge slots + ch pads
            #pragma unroll 1
            for (int i = tid; i < 648; i += 512) {
                int addr_sh;
                if (i < 120) {
                    int r = i / 30, rem = i % 30;
                    int s = (rem / 15) * 65;
                    addr_sh = (r * 66 + s) * 120 + (rem % 15) * 8;
                } else {
                    int z = i - 120;
                    addr_sh = (z >> 1) * 120 + 104 + (z & 1) * 8;
                }
                *(i32x4*)(&lds[addr_sh]) = z4;
            }
        }
        // x staging: 512 items (skip on final out-only pass)
        if (tt < T_) {
            int ch = tid & 7, q = (tid >> 3) & 15, r = tid >> 7;
            int y = y0 - 1 + r;
            short v0 = 0, v1 = 0, v2 = 0, v3 = 0;
            if ((unsigned)y < 64u) {
                size_t base = ((size_t)(b * T_ + tt) * COUT + ch) * HW + y * 64 + q * 4;
                if (f32) {
                    float4 f = *(const float4*)((const float*)xd + base);
                    v0 = f2bs(f.x); v1 = f2bs(f.y); v2 = f2bs(f.z); v3 = f2bs(f.w);
                } else {
                    short4 sv = *(const short4*)((const short*)xd + base);
                    v0 = sv.x; v1 = sv.y; v2 = sv.z; v3 = sv.w;
                }
            }
            int sb = r * 66 + 1 + q * 4;
            lds[(sb + 0) * 120 + ch] = v0;
            lds[(sb + 1) * 120 + ch] = v1;
            lds[(sb + 2) * 120 + ch] = v2;
            lds[(sb + 3) * 120 + ch] = v3;
        }

        // neighbor sync: need h_{tt-1} of bands band+-1 published (prog>=tt+1)
        if (tid < 2) {
            int nb = band + (tid ? 1 : -1);
            if ((unsigned)nb < 32u)
                wait_prog(prog + (((nb << 3) | b) << 4), tt + 1);
        }
        __syncthreads();

        if (tt == 0) {
            // full h staging: 3072 chunks, 6 per thread
            i32x4 tmp[6]; int ss2[6], jj2[6];
            #pragma unroll
            for (int i = 0; i < 6; i++) {
                int c2 = tid + i * 512;
                int s = c2 / 12, j = c2 - s * 12;
                ss2[i] = s; jj2[i] = j;
                int y = y0 - 1 + (s >> 6);
                if ((unsigned)y < 64u)
                    tmp[i] = ldB16(hR + ((size_t)b * HW + (size_t)y * 64 + (s & 63)) * 96 + j * 8);
                else tmp[i] = z4;
            }
            vm0();
            #pragma unroll
            for (int i = 0; i < 6; i++) {
                int s = ss2[i];
                *(i32x4*)(&lds[((s >> 6) * 66 + 1 + (s & 63)) * 120 + 8 + jj2[i] * 8]) = tmp[i];
            }
        } else {
            // halo staging: rows y0-1 (slot 0) and y0+2 (slot 3); 3 per thread
            i32x4 tmp[3]; int ss2[3], jj2[3];
            #pragma unroll
            for (int i = 0; i < 3; i++) {
                int c2 = tid + i * 512;           // 0..1535
                int s = c2 / 12, j = c2 - s * 12; // s 0..127
                int hi = s >> 6;
                int y = hi ? (y0 + 2) : (y0 - 1);
                ss2[i] = hi * 3 * 66 + 1 + (s & 63);
                jj2[i] = j;
                if ((unsigned)y < 64u)
                    tmp[i] = ldB16(hR + ((size_t)b * HW + (size_t)y * 64 + (s & 63)) * 96 + j * 8);
                else tmp[i] = z4;
            }
            vm0();
            #pragma unroll
            for (int i = 0; i < 3; i++)
                *(i32x4*)(&lds[ss2[i] * 120 + 8 + jj2[i] * 8]) = tmp[i];
        }
        __syncthreads();

        const int rw = 1 + (wv >> 1);
        const int x0 = (wv & 1) * 32;

        // UNIONED accumulators: grp0 f=A[0..2],i=A[3..5]; grp1 g=A[0..2],
        // o=A[3..5], out=A[6]. 112 acc regs (vs 208 split) -> no spills.
        f32x16 A[7];
        #pragma unroll
        for (int m = 0; m < 7; m++)
            #pragma unroll
            for (int r = 0; r < 16; r++) A[m][r] = 0.f;

        // ---- MFMA phase (no barriers inside; groups diverge at wave level)
        if (grp == 0 && tt < T_) {
            // f,i tiles (mt 0-5), taps 0-8 x k0 0-6, 1-deep prefetch
            bf16x8 cA[6], cB;
            cB = *(const bf16x8*)(&lds[((rw - 1) * 66 + x0 + n) * 120] + kj * 8);
            #pragma unroll
            for (int m = 0; m < 6; m++)
                cA[m] = *(const bf16x8*)(WtA + (size_t)m * 512 + lane * 8);
            #pragma unroll 1
            for (int u = 0; u < 63; u++) {
                int un = (u < 62) ? u + 1 : 62;
                int tapn = un / 7, k0n = un - tapn * 7;
                int dyn_ = tapn / 3 - 1, dxn = tapn - (tapn / 3) * 3 - 1;
                bf16x8 nA[6], nB;
                nB = *(const bf16x8*)(&lds[((rw + dyn_) * 66 + 1 + x0 + n + dxn) * 120]
                                      + k0n * 16 + kj * 8);
                #pragma unroll
                for (int m = 0; m < 6; m++)
                    nA[m] = *(const bf16x8*)(WtA + ((size_t)un * 12 + m) * 512 + lane * 8);
                #pragma unroll
                for (int m = 0; m < 6; m++) mfma_a(A[m], cA[m], cB);
                #pragma unroll
                for (int m = 0; m < 6; m++) cA[m] = nA[m];
                cB = nB;
            }
        }
        if (grp == 1) {
            // g tiles (mt 6-8) -> A[0..2], out head -> A[6]
            bf16x8 cG[3], cK, cB;
            cB = *(const bf16x8*)(&lds[((rw - 1) * 66 + x0 + n) * 120] + kj * 8);
            #pragma unroll
            for (int m = 0; m < 3; m++)
                cG[m] = *(const bf16x8*)(WtA + (size_t)(6 + m) * 512 + lane * 8);
            cK = *(const bf16x8*)(K2A + lane * 8);
            #pragma unroll 1
            for (int u = 0; u < 63; u++) {
                int un = (u < 62) ? u + 1 : 62;
                int tapn = un / 7, k0n = un - tapn * 7;
                int dyn_ = tapn / 3 - 1, dxn = tapn - (tapn / 3) * 3 - 1;
                bf16x8 nG[3], nK, nB;
                nB = *(const bf16x8*)(&lds[((rw + dyn_) * 66 + 1 + x0 + n + dxn) * 120]
                                      + k0n * 16 + kj * 8);
                #pragma unroll
                for (int m = 0; m < 3; m++)
                    nG[m] = *(const bf16x8*)(WtA + ((size_t)un * 12 + 6 + m) * 512 + lane * 8);
                nK = *(const bf16x8*)(K2A + (size_t)un * 512 + lane * 8);
                if (tt < T_) {
                    #pragma unroll
                    for (int m = 0; m < 3; m++) mfma_a(A[m], cG[m], cB);
                }
                if (tt > 0) mfma_a(A[6], cK, cB);
                #pragma unroll
                for (int m = 0; m < 3; m++) cG[m] = nG[m];
                cK = nK; cB = nB;
            }
            // o tiles (mt 9-11) -> A[3..5]: center tap only
            if (tt < T_) {
                const short* recc = &lds[(rw * 66 + 1 + x0 + n) * 120];
                bf16x8 cO[3], cB2 = *(const bf16x8*)(recc + kj * 8);
                #pragma unroll
                for (int m = 0; m < 3; m++)
                    cO[m] = *(const bf16x8*)(WtA + ((size_t)28 * 12 + 9 + m) * 512 + lane * 8);
                #pragma unroll
                for (int k0 = 0; k0 < 7; k0++) {
                    bf16x8 nO[3], nB2;
                    if (k0 < 6) {
                        nB2 = *(const bf16x8*)(recc + (k0 + 1) * 16 + kj * 8);
                        #pragma unroll
                        for (int m = 0; m < 3; m++)
                            nO[m] = *(const bf16x8*)(WtA + ((size_t)(29 + k0) * 12 + 9 + m) * 512 + lane * 8);
                    }
                    #pragma unroll
                    for (int m = 0; m < 3; m++) mfma_a(A[3 + m], cO[m], cB2);
                    if (k0 < 6) {
                        #pragma unroll
                        for (int m = 0; m < 3; m++) cO[m] = nO[m];
                        cB2 = nB2;
                    }
                }
            }
        }
        __syncthreads();

        // B publishes gate activations (g = A[0..2], o = A[3..5])
        if (grp == 1 && tt < T_) {
            #pragma unroll
            for (int dt = 0; dt < 3; dt++)
                #pragma unroll
                for (int r = 0; r < 16; r++) {
                    int row = (r & 3) + 8 * (r >> 2) + 4 * kj;
                    int d = dt * 32 + row;
                    xg[px * 97 + d] = tanhf_(A[dt][r]     + dbc[d]);
                    xo[px * 97 + d] = sigmf_(A[3 + dt][r] + dbo[d]);
                }
        }
        __syncthreads();

        // B: fused out store for step tt-1 (A[6]) || A: LSTM pointwise
        if (grp == 1 && tt > 0) {
            #pragma unroll
            for (int r = 0; r < 4; r++) {
                int o = r + 4 * kj;
                float v = A[6][r] + b2[o];
                size_t oadr = ((size_t)(b * T_ + (tt - 1)) * COUT + o) * HW + pg;
                if (f32) ((float*)out)[oadr] = v;
                else     ((bf16*)out)[oadr] = __float2bfloat16(v);
            }
        }
        if (grp == 0 && tt < T_) {
            #pragma unroll
            for (int dt = 0; dt < 3; dt++)
                #pragma unroll
                for (int r = 0; r < 16; r++) {
                    int row = (r & 3) + 8 * (r >> 2) + 4 * kj;
                    int d = dt * 32 + row;
                    float fg = sigmf_(A[dt][r]     + dbf[d]);
                    float ig = sigmf_(A[3 + dt][r] + dbi[d]);
                    int ci = dt * 16 + r;
                    float cn = fmaf(cre[ci], fg, ig * xg[px * 97 + d]);
                    cre[ci] = cn;
                    lds[((1 + (px >> 6)) * 66 + 1 + (px & 63)) * 120 + 8 + d]
                        = f2bs(tanhf_(cn) * xo[px * 97 + d]);
                }
        }
        __syncthreads();

        if (tt < T_) {
            // publish own 2 rows: 128 recs x 12 parts x 16B = full 96 ch
            #pragma unroll 1
            for (int c = tid; c < 1536; c += 512) {
                int rec2 = c / 12, part = c - (c / 12) * 12;
                stB16(hWr + ((size_t)b * HW + pix0 + rec2) * 96 + part * 8,
                      *(const i32x4*)(&lds[((1 + (rec2 >> 6)) * 66 + 1 + (rec2 & 63)) * 120
                                           + 8 + part * 8]));
            }
            vm0();
            __syncthreads();
            if (tid == 0)
                __hip_atomic_store(&prog[blockIdx.x * 16], tt + 2,
                                   __ATOMIC_RELAXED, __HIP_MEMORY_SCOPE_AGENT);
        }
    }
}

// ---------------------------------------------------------------------------
extern "C" void kernel_launch(void* const* d_in, const int* in_sizes, int n_in,
                              void* d_out, int out_size, void* d_ws, size_t ws_size,
                              hipStream_t stream)
{
    const void* enc_in = d_in[0];
    const void* dec_in = d_in[1];
    const void* eWf = d_in[2];  const void* ebf_ = d_in[3];
    const void* eWi = d_in[4];  const void* ebi_ = d_in[5];
    const void* eWc = d_in[6];  const void* ebc_ = d_in[7];
    const void* eWo = d_in[8];  const void* ebo_ = d_in[9];
    const void* dKf = d_in[10]; const void* dbf_ = d_in[11];
    const void* dKi = d_in[12]; const void* dbi_ = d_in[13];
    const void* dKc = d_in[14]; const void* dbc_ = d_in[15];
    const void* dWo = d_in[16]; const void* dbo_ = d_in[17];
    const void* oK  = d_in[18]; const void* obv = d_in[19];
    const void* lW  = d_in[20]; const void* lb  = d_in[21];

    int* flag = (int*)d_ws;
    int* prog = (int*)d_ws + 16;             // 256 slots x 16 ints (64B stride)
    float* ws = (float*)d_ws + 16 + 4096;

    const int S = B_ * HD * HW;              // 3,145,728 state elems
    short* hPA = (short*)ws;                 // S shorts (pixel-major h)
    short* hPB = (short*)(ws + S / 2);       // S shorts
    float* biases = ws + S;                  // 8 x 96 fp32
    float* b2   = biases + 768;              // 16
    short* WtA  = (short*)(b2 + 16);                  // 387,072 shorts
    short* EW   = (short*)(b2 + 16 + 193536);         // 43,008 shorts
    short* K2A  = (short*)(b2 + 16 + 193536 + 21504); // 32,256 shorts

    hipFuncSetAttribute(reinterpret_cast<const void*>(net_k),
                        hipFuncAttributeMaxDynamicSharedMemorySize, LDS_BYTES);

    setup_k<<<dim3(231), dim3(256), 0, stream>>>(
        eWf, ebf_, eWi, ebi_, eWc, ebc_, eWo, ebo_,
        dKf, dbf_, dKi, dbi_, dKc, dbc_, dWo, dbo_,
        oK, obv, lW, lb,
        biases, b2, EW, WtA, K2A, flag, prog);

    net_k<<<dim3(256), dim3(512), LDS_BYTES, stream>>>(
        enc_in, dec_in, hPA, hPB, d_out,
        EW, WtA, K2A,
        biases + 0, biases + 96, biases + 192, biases + 288,
        biases + 384, biases + 480, biases + 576, biases + 672,
        b2, flag, prog);
}

// Round 13
// 2164.480 us; speedup vs baseline: 1.2593x; 1.0163x over previous
//
#include <hip/hip_runtime.h>
#include <hip/hip_bf16.h>

#define B_   8
#define T_   12
#define CIN  16
#define HD   96
#define COUT 8
#define CE   112
#define CD   104
#define HW   4096
#define WIMG 64

// LDS (bytes): tile 63,360 | gate-exchange 2 x 128 x 97 f32 = 99,328 -> 162,688
#define TILE_SH 31680
#define XG_F    12416            // 128 * 97 floats per exchange plane
#define LDS_BYTES (63360 + 2 * XG_F * 4)

typedef __hip_bfloat16 bf16;
typedef __attribute__((ext_vector_type(8))) short bf16x8;   // 8 bf16 (4 VGPRs)
typedef __attribute__((ext_vector_type(16))) float f32x16;  // MFMA 32x32 C/D
typedef __attribute__((ext_vector_type(4))) int i32x4;      // 16B payload

__device__ __forceinline__ float b2f(bf16 v) { return __bfloat162float(v); }
__device__ __forceinline__ float sigmf_(float x) { return 1.0f / (1.0f + __expf(-x)); }
__device__ __forceinline__ float tanhf_(float x) { return 2.0f / (1.0f + __expf(-2.0f * x)) - 1.0f; }

__device__ __forceinline__ float ldin(const void* p, long i, int f32) {
    return f32 ? ((const float*)p)[i] : b2f(((const bf16*)p)[i]);
}
__device__ __forceinline__ short f2bs(float v) {
    __hip_bfloat16 hv = __float2bfloat16(v);
    return *reinterpret_cast<short*>(&hv);
}

// MFMA with "+a": accumulators in AGPRs
__device__ __forceinline__ void mfma_a(f32x16& acc, bf16x8 a, bf16x8 b) {
    asm("v_mfma_f32_32x32x16_bf16 %0, %1, %2, %0"
        : "+a"(acc) : "v"(a), "v"(b));
}

// 16B device-coherent (bypass) loads/stores for cross-block h exchange.
__device__ __forceinline__ i32x4 ldB16(const short* p) {
    i32x4 r;
    asm volatile("global_load_dwordx4 %0, %1, off sc0 sc1"
                 : "=v"(r) : "v"(p) : "memory");
    return r;
}
__device__ __forceinline__ void stB16(short* p, i32x4 v) {
    asm volatile("global_store_dwordx4 %0, %1, off sc0 sc1"
                 :: "v"(p), "v"(v) : "memory");
}
__device__ __forceinline__ void vm0() {
    asm volatile("s_waitcnt vmcnt(0)" ::: "memory");
}

// neighbor-pair progress sync (per-block counter on its own 64B line).
__device__ __forceinline__ void wait_prog(const int* p, int need) {
    while (__hip_atomic_load(p, __ATOMIC_RELAXED, __HIP_MEMORY_SCOPE_AGENT) < need)
        __builtin_amdgcn_s_sleep(1);
}

__device__ __forceinline__ int detect_flag(const void* w) {
    const unsigned short* u = (const unsigned short*)w;
    int bad = 0;
    for (int i = 0; i < 64; i++) {
        unsigned short v = u[i];
        unsigned e = (v >> 7) & 0xFF;
        if (!(v == 0 || (e >= 90 && e <= 128))) bad++;
    }
    return (bad > 8) ? 1 : 0;
}

// ---------------------------------------------------------------------------
// ONE fused setup kernel (unchanged layouts). Block ranges:
//   0-2: biases  3: b2+flag  4: prog zero  5-25: EW  26-214: WtA  215-230: K2A
// ---------------------------------------------------------------------------
__global__ void setup_k(
    const void* eWf, const void* ebf_, const void* eWi, const void* ebi_,
    const void* eWc, const void* ebc_, const void* eWo, const void* ebo_,
    const void* dKf, const void* dbf_, const void* dKi, const void* dbi_,
    const void* dKc, const void* dbc_, const void* dWo, const void* dbo_,
    const void* oK,  const void* obv,  const void* lW,  const void* lb,
    float* __restrict__ biases, float* __restrict__ b2,
    short* __restrict__ EW, short* __restrict__ WtA, short* __restrict__ K2A,
    int* __restrict__ flag, int* __restrict__ prog)
{
    const int f = detect_flag(eWf);
    const int bid = blockIdx.x, tid = threadIdx.x;

    if (bid < 3) {
        int idx = bid * 256 + tid;
        if (idx < 768) {
            const void* srcs[8] = {ebf_, ebi_, ebc_, ebo_, dbf_, dbi_, dbc_, dbo_};
            biases[idx] = ldin(srcs[idx / 96], idx % 96, f);
        }
        return;
    }
    if (bid == 3) {
        if (tid < COUT) {
            float a = ldin(lb, tid, f);
            for (int cd = 0; cd < CD; cd++)
                a = fmaf(ldin(obv, cd, f), ldin(lW, cd * COUT + tid, f), a);
            b2[tid] = a;
        }
        if (tid == 32) *flag = f;
        return;
    }
    if (bid == 4) {
        __hip_atomic_store(&prog[tid * 16], 0, __ATOMIC_RELAXED, __HIP_MEMORY_SCOPE_AGENT);
        return;
    }
    if (bid < 26) {                              // EW
        int lin = (bid - 5) * 256 + tid;
        if (lin >= 7 * 12 * 64) return;
        int lane = lin & 63;
        int rest = lin >> 6;
        int mt = rest % 12;
        int k0 = rest / 12;
        int m = mt * 32 + (lane & 31);
        int gate = m / 96, d = m % 96;
        int chb = k0 * 16 + (lane >> 5) * 8;
        const void* W = (gate == 0) ? eWf : (gate == 1) ? eWi : (gate == 2) ? eWc : eWo;
        #pragma unroll
        for (int j = 0; j < 8; j++)
            EW[(size_t)lin * 8 + j] = f2bs(ldin(W, (size_t)(chb + j) * HD + d, f));
        return;
    }
    if (bid < 215) {                             // WtA
        int lin = (bid - 26) * 256 + tid;
        if (lin >= 9 * 7 * 12 * 64) return;
        int lane = lin & 63;
        int rest = lin >> 6;
        int mt  = rest % 12;
        int k07 = rest / 12;
        int k0  = k07 % 7;
        int tap = k07 / 7;
        int m = mt * 32 + (lane & 31);
        int gate = m / 96, d = m % 96;
        int chb = k0 * 16 + (lane >> 5) * 8;
        #pragma unroll
        for (int j = 0; j < 8; j++) {
            int ch = chb + j;
            float v = 0.f;
            if (ch < 104) {
                long ki = ((long)d * CD + ch) * 9 + tap;
                if (gate == 0)      v = ldin(dKf, ki, f);
                else if (gate == 1) v = ldin(dKi, ki, f);
                else if (gate == 2) v = ldin(dKc, ki, f);
                else                v = (tap == 4) ? ldin(dWo, (long)ch * HD + d, f) : 0.f;
            }
            WtA[(size_t)lin * 8 + j] = f2bs(v);
        }
        return;
    }
    {                                            // K2A with combine inline
        int lin = (bid - 215) * 256 + tid;
        if (lin >= 9 * 7 * 64) return;
        int lane = lin & 63;
        int rest = lin >> 6;
        int k0 = rest % 7;
        int tap = rest / 7;
        int m = lane & 31;
        int kb = k0 * 16 + (lane >> 5) * 8;
        #pragma unroll 1
        for (int j = 0; j < 8; j++) {
            int c = kb + j - 8;
            float v = 0.f;
            if (m < 8 && c >= 0 && c < 96) {
                long i = (long)c * 9 + tap;
                for (int cd = 0; cd < CD; cd++)
                    v = fmaf(ldin(oK, (long)cd * (HD * 9) + i, f),
                             ldin(lW, (long)cd * COUT + m, f), v);
            }
            K2A[(size_t)lin * 8 + j] = f2bs(v);
        }
    }
}

// ---------------------------------------------------------------------------
// persistent kernel, 8-wave M-SPLIT blocks: 512 threads, grid 256 (1/CU).
// Group A (waves 0-3): f,i gate tiles + c-state + h-write, for px 0..127.
// Group B (waves 4-7): g,o gate tiles + out-head, SAME px; exchange via LDS.
// NO manual prefetch: at 2 waves/SIMD latency hiding is the co-wave's job
// (TLP). This keeps arch VGPRs <= 128 so cre[48] stays in registers --
// R11/R12's 0.5-4.6 GB of scratch traffic was cre spilling under the
// 256-reg/wave unified budget (per-SIMD file = 512 regs, m69).
// Per-accumulator MFMA order identical to prior rounds -> bit-identical out.
// ---------------------------------------------------------------------------
__global__ void __launch_bounds__(512, 2) net_k(
    const void* __restrict__ xe, const void* __restrict__ xd,
    short* __restrict__ hPA, short* __restrict__ hPB,
    void* __restrict__ out,
    const short* __restrict__ EW, const short* __restrict__ WtA,
    const short* __restrict__ K2A,
    const float* __restrict__ ebf, const float* __restrict__ ebi,
    const float* __restrict__ ebc, const float* __restrict__ ebo,
    const float* __restrict__ dbf, const float* __restrict__ dbi,
    const float* __restrict__ dbc, const float* __restrict__ dbo,
    const float* __restrict__ b2, const int* __restrict__ flag,
    int* __restrict__ prog)
{
    extern __shared__ short lds[];            // 162,688 B dynamic
    float* xg = (float*)(lds + TILE_SH);      // gate-exchange: tanh(g)
    float* xo = xg + XG_F;                    // gate-exchange: sigm(o)
    const int f32 = *flag;
    const int tid  = threadIdx.x;
    const int b    = blockIdx.x & 7;
    const int band = blockIdx.x >> 3;         // 0..31
    const int y0   = band * 2;
    const int pix0 = y0 * 64;
    const int wave = tid >> 6, lane = tid & 63;
    const int grp  = wave >> 2;               // 0 = f,i/c-owner  1 = g,o/out
    const int wv   = wave & 3;
    const int n = lane & 31, kj = lane >> 5;
    const int px = wv * 32 + n;               // block-local pixel 0..127
    const int pg = pix0 + px;                 // global pixel
    const i32x4 z4 = {0, 0, 0, 0};

    float cre[48];
    #pragma unroll
    for (int i = 0; i < 48; i++) cre[i] = 0.f;

    // ================= encoder phase =====
    #pragma unroll 1
    for (int t = 0; t < T_; t++) {
        // x staging: 512 items, one per thread
        {
            int ch = tid & 15, q = tid >> 4;
            size_t base = ((size_t)(b * T_ + t) * CIN + ch) * HW + pix0 + q * 4;
            short v0, v1, v2, v3;
            if (f32) {
                float4 f = *(const float4*)((const float*)xe + base);
                v0 = f2bs(f.x); v1 = f2bs(f.y); v2 = f2bs(f.z); v3 = f2bs(f.w);
            } else {
                short4 sv = *(const short4*)((const short*)xe + base);
                v0 = sv.x; v1 = sv.y; v2 = sv.z; v3 = sv.w;
            }
            int sb = q * 4;
            lds[(sb + 0) * 120 + ch] = v0;
            lds[(sb + 1) * 120 + ch] = v1;
            lds[(sb + 2) * 120 + ch] = v2;
            lds[(sb + 3) * 120 + ch] = v3;
        }
        __syncthreads();

        f32x16 acc[6];
        #pragma unroll
        for (int m = 0; m < 6; m++)
            #pragma unroll
            for (int r = 0; r < 16; r++) acc[m][r] = 0.f;

        const short* rec = &lds[px * 120];
        const int mt0 = grp * 6;
        const int k0max = (t == 0) ? 1 : 7;
        #pragma unroll 1
        for (int k0 = 0; k0 < k0max; k0++) {
            bf16x8 bB = *(const bf16x8*)(rec + k0 * 16 + kj * 8);
            #pragma unroll
            for (int m = 0; m < 6; m++)
                mfma_a(acc[m], *(const bf16x8*)(EW + (size_t)(k0 * 12 + mt0 + m) * 512 + lane * 8), bB);
        }
        __syncthreads();

        // B publishes gate activations
        if (grp == 1) {
            #pragma unroll
            for (int dt = 0; dt < 3; dt++)
                #pragma unroll
                for (int r = 0; r < 16; r++) {
                    int row = (r & 3) + 8 * (r >> 2) + 4 * kj;
                    int d = dt * 32 + row;
                    xg[px * 97 + d] = tanhf_(acc[dt][r]     + ebc[d]);
                    xo[px * 97 + d] = sigmf_(acc[3 + dt][r] + ebo[d]);
                }
        }
        __syncthreads();
        // A: LSTM pointwise, c in regs, h -> own LDS rec (+16 offset)
        if (grp == 0) {
            #pragma unroll
            for (int dt = 0; dt < 3; dt++)
                #pragma unroll
                for (int r = 0; r < 16; r++) {
                    int row = (r & 3) + 8 * (r >> 2) + 4 * kj;
                    int d = dt * 32 + row;
                    float fg = sigmf_(acc[dt][r]     + ebf[d]);
                    float ig = sigmf_(acc[3 + dt][r] + ebi[d]);
                    int ci = dt * 16 + r;
                    float cn = fmaf(cre[ci], fg, ig * xg[px * 97 + d]);
                    cre[ci] = cn;
                    lds[px * 120 + 16 + d] = f2bs(tanhf_(cn) * xo[px * 97 + d]);
                }
        }
        __syncthreads();
        if (t == T_ - 1) {
            // publish final enc h: 128 recs x 12 parts x 16B = full 96 ch
            #pragma unroll 1
            for (int c = tid; c < 1536; c += 512) {
                int rec2 = c / 12, part = c - (c / 12) * 12;
                stB16(hPA + ((size_t)b * HW + pix0 + rec2) * 96 + part * 8,
                      *(const i32x4*)(&lds[rec2 * 120 + 16 + part * 8]));
            }
        }
    }
    vm0();
    __syncthreads();
    if (tid == 0)
        __hip_atomic_store(&prog[blockIdx.x * 16], 1, __ATOMIC_RELAXED, __HIP_MEMORY_SCOPE_AGENT);

    // ================= decoder phase =====
    #pragma unroll 1
    for (int tt = 0; tt <= T_; tt++) {
        short* hR  = (tt & 1) ? hPB : hPA;    // h_{tt-1}
        short* hWr = (tt & 1) ? hPA : hPB;    // h_tt

        if (tt == 0) {
            // zero pass: edge slots + ch pads
            #pragma unroll 1
            for (int i = tid; i < 648; i += 512) {
                int addr_sh;
                if (i < 120) {
                    int r = i / 30, rem = i % 30;
                    int s = (rem / 15) * 65;
                    addr_sh = (r * 66 + s) * 120 + (rem % 15) * 8;
                } else {
                    int z = i - 120;
                    addr_sh = (z >> 1) * 120 + 104 + (z & 1) * 8;
                }
                *(i32x4*)(&lds[addr_sh]) = z4;
            }
        }
        // x staging: 512 items (skip on final out-only pass)
        if (tt < T_) {
            int ch = tid & 7, q = (tid >> 3) & 15, r = tid >> 7;
            int y = y0 - 1 + r;
            short v0 = 0, v1 = 0, v2 = 0, v3 = 0;
            if ((unsigned)y < 64u) {
                size_t base = ((size_t)(b * T_ + tt) * COUT + ch) * HW + y * 64 + q * 4;
                if (f32) {
                    float4 f = *(const float4*)((const float*)xd + base);
                    v0 = f2bs(f.x); v1 = f2bs(f.y); v2 = f2bs(f.z); v3 = f2bs(f.w);
                } else {
                    short4 sv = *(const short4*)((const short*)xd + base);
                    v0 = sv.x; v1 = sv.y; v2 = sv.z; v3 = sv.w;
                }
            }
            int sb = r * 66 + 1 + q * 4;
            lds[(sb + 0) * 120 + ch] = v0;
            lds[(sb + 1) * 120 + ch] = v1;
            lds[(sb + 2) * 120 + ch] = v2;
            lds[(sb + 3) * 120 + ch] = v3;
        }

        // neighbor sync: need h_{tt-1} of bands band+-1 published (prog>=tt+1)
        if (tid < 2) {
            int nb = band + (tid ? 1 : -1);
            if ((unsigned)nb < 32u)
                wait_prog(prog + (((nb << 3) | b) << 4), tt + 1);
        }
        __syncthreads();

        if (tt == 0) {
            // full h staging: 3072 chunks, 6 per thread
            i32x4 tmp[6]; int ss2[6], jj2[6];
            #pragma unroll
            for (int i = 0; i < 6; i++) {
                int c2 = tid + i * 512;
                int s = c2 / 12, j = c2 - s * 12;
                ss2[i] = s; jj2[i] = j;
                int y = y0 - 1 + (s >> 6);
                if ((unsigned)y < 64u)
                    tmp[i] = ldB16(hR + ((size_t)b * HW + (size_t)y * 64 + (s & 63)) * 96 + j * 8);
                else tmp[i] = z4;
            }
            vm0();
            #pragma unroll
            for (int i = 0; i < 6; i++) {
                int s = ss2[i];
                *(i32x4*)(&lds[((s >> 6) * 66 + 1 + (s & 63)) * 120 + 8 + jj2[i] * 8]) = tmp[i];
            }
        } else {
            // halo staging: rows y0-1 (slot 0) and y0+2 (slot 3); 3 per thread
            i32x4 tmp[3]; int ss2[3], jj2[3];
            #pragma unroll
            for (int i = 0; i < 3; i++) {
                int c2 = tid + i * 512;           // 0..1535
                int s = c2 / 12, j = c2 - s * 12; // s 0..127
                int hi = s >> 6;
                int y = hi ? (y0 + 2) : (y0 - 1);
                ss2[i] = hi * 3 * 66 + 1 + (s & 63);
                jj2[i] = j;
                if ((unsigned)y < 64u)
                    tmp[i] = ldB16(hR + ((size_t)b * HW + (size_t)y * 64 + (s & 63)) * 96 + j * 8);
                else tmp[i] = z4;
            }
            vm0();
            #pragma unroll
            for (int i = 0; i < 3; i++)
                *(i32x4*)(&lds[ss2[i] * 120 + 8 + jj2[i] * 8]) = tmp[i];
        }
        __syncthreads();

        const int rw = 1 + (wv >> 1);
        const int x0 = (wv & 1) * 32;

        // UNIONED accumulators: grp0 f=A[0..2],i=A[3..5] (A[6] dead there);
        // grp1 g=A[0..2], o=A[3..5], out=A[6].
        f32x16 A[7];
        #pragma unroll
        for (int m = 0; m < 6; m++)
            #pragma unroll
            for (int r = 0; r < 16; r++) A[m][r] = 0.f;

        // ---- MFMA phase (no barriers inside; groups diverge at wave level)
        if (grp == 0 && tt < T_) {
            // f,i tiles (mt 0-5), u = tap*7+k0 ascending (same acc order)
            #pragma unroll 1
            for (int u = 0; u < 63; u++) {
                int tap = u / 7, k0 = u - tap * 7;
                int dy = tap / 3 - 1, dx = tap - (tap / 3) * 3 - 1;
                bf16x8 bB = *(const bf16x8*)(&lds[((rw + dy) * 66 + 1 + x0 + n + dx) * 120]
                                             + k0 * 16 + kj * 8);
                #pragma unroll
                for (int m = 0; m < 6; m++)
                    mfma_a(A[m], *(const bf16x8*)(WtA + ((size_t)u * 12 + m) * 512 + lane * 8), bB);
            }
        }
        if (grp == 1) {
            #pragma unroll
            for (int r = 0; r < 16; r++) A[6][r] = 0.f;
            // g tiles (mt 6-8) -> A[0..2], out head -> A[6]
            #pragma unroll 1
            for (int u = 0; u < 63; u++) {
                int tap = u / 7, k0 = u - tap * 7;
                int dy = tap / 3 - 1, dx = tap - (tap / 3) * 3 - 1;
                bf16x8 bB = *(const bf16x8*)(&lds[((rw + dy) * 66 + 1 + x0 + n + dx) * 120]
                                             + k0 * 16 + kj * 8);
                if (tt < T_) {
                    #pragma unroll
                    for (int m = 0; m < 3; m++)
                        mfma_a(A[m], *(const bf16x8*)(WtA + ((size_t)u * 12 + 6 + m) * 512 + lane * 8), bB);
                }
                if (tt > 0)
                    mfma_a(A[6], *(const bf16x8*)(K2A + (size_t)u * 512 + lane * 8), bB);
            }
            // o tiles (mt 9-11) -> A[3..5]: center tap only (u = 28..34)
            if (tt < T_) {
                const short* recc = &lds[(rw * 66 + 1 + x0 + n) * 120];
                #pragma unroll 1
                for (int k0 = 0; k0 < 7; k0++) {
                    bf16x8 bB2 = *(const bf16x8*)(recc + k0 * 16 + kj * 8);
                    #pragma unroll
                    for (int m = 0; m < 3; m++)
                        mfma_a(A[3 + m], *(const bf16x8*)(WtA + ((size_t)(28 + k0) * 12 + 9 + m) * 512 + lane * 8), bB2);
                }
            }
        }
        __syncthreads();

        // B publishes gate activations (g = A[0..2], o = A[3..5])
        if (grp == 1 && tt < T_) {
            #pragma unroll
            for (int dt = 0; dt < 3; dt++)
                #pragma unroll
                for (int r = 0; r < 16; r++) {
                    int row = (r & 3) + 8 * (r >> 2) + 4 * kj;
                    int d = dt * 32 + row;
                    xg[px * 97 + d] = tanhf_(A[dt][r]     + dbc[d]);
                    xo[px * 97 + d] = sigmf_(A[3 + dt][r] + dbo[d]);
                }
        }
        __syncthreads();

        // B: fused out store for step tt-1 (A[6]) || A: LSTM pointwise
        if (grp == 1 && tt > 0) {
            #pragma unroll
            for (int r = 0; r < 4; r++) {
                int o = r + 4 * kj;
                float v = A[6][r] + b2[o];
                size_t oadr = ((size_t)(b * T_ + (tt - 1)) * COUT + o) * HW + pg;
                if (f32) ((float*)out)[oadr] = v;
                else     ((bf16*)out)[oadr] = __float2bfloat16(v);
            }
        }
        if (grp == 0 && tt < T_) {
            #pragma unroll
            for (int dt = 0; dt < 3; dt++)
                #pragma unroll
                for (int r = 0; r < 16; r++) {
                    int row = (r & 3) + 8 * (r >> 2) + 4 * kj;
                    int d = dt * 32 + row;
                    float fg = sigmf_(A[dt][r]     + dbf[d]);
                    float ig = sigmf_(A[3 + dt][r] + dbi[d]);
                    int ci = dt * 16 + r;
                    float cn = fmaf(cre[ci], fg, ig * xg[px * 97 + d]);
                    cre[ci] = cn;
                    lds[((1 + (px >> 6)) * 66 + 1 + (px & 63)) * 120 + 8 + d]
                        = f2bs(tanhf_(cn) * xo[px * 97 + d]);
                }
        }
        __syncthreads();

        if (tt < T_) {
            // publish own 2 rows: 128 recs x 12 parts x 16B = full 96 ch
            #pragma unroll 1
            for (int c = tid; c < 1536; c += 512) {
                int rec2 = c / 12, part = c - (c / 12) * 12;
                stB16(hWr + ((size_t)b * HW + pix0 + rec2) * 96 + part * 8,
                      *(const i32x4*)(&lds[((1 + (rec2 >> 6)) * 66 + 1 + (rec2 & 63)) * 120
                                           + 8 + part * 8]));
            }
            vm0();
            __syncthreads();
            if (tid == 0)
                __hip_atomic_store(&prog[blockIdx.x * 16], tt + 2,
                                   __ATOMIC_RELAXED, __HIP_MEMORY_SCOPE_AGENT);
        }
    }
}

// ---------------------------------------------------------------------------
extern "C" void kernel_launch(void* const* d_in, const int* in_sizes, int n_in,
                              void* d_out, int out_size, void* d_ws, size_t ws_size,
                              hipStream_t stream)
{
    const void* enc_in = d_in[0];
    const void* dec_in = d_in[1];
    const void* eWf = d_in[2];  const void* ebf_ = d_in[3];
    const void* eWi = d_in[4];  const void* ebi_ = d_in[5];
    const void* eWc = d_in[6];  const void* ebc_ = d_in[7];
    const void* eWo = d_in[8];  const void* ebo_ = d_in[9];
    const void* dKf = d_in[10]; const void* dbf_ = d_in[11];
    const void* dKi = d_in[12]; const void* dbi_ = d_in[13];
    const void* dKc = d_in[14]; const void* dbc_ = d_in[15];
    const void* dWo = d_in[16]; const void* dbo_ = d_in[17];
    const void* oK  = d_in[18]; const void* obv = d_in[19];
    const void* lW  = d_in[20]; const void* lb  = d_in[21];

    int* flag = (int*)d_ws;
    int* prog = (int*)d_ws + 16;             // 256 slots x 16 ints (64B stride)
    float* ws = (float*)d_ws + 16 + 4096;

    const int S = B_ * HD * HW;              // 3,145,728 state elems
    short* hPA = (short*)ws;                 // S shorts (pixel-major h)
    short* hPB = (short*)(ws + S / 2);       // S shorts
    float* biases = ws + S;                  // 8 x 96 fp32
    float* b2   = biases + 768;              // 16
    short* WtA  = (short*)(b2 + 16);                  // 387,072 shorts
    short* EW   = (short*)(b2 + 16 + 193536);         // 43,008 shorts
    short* K2A  = (short*)(b2 + 16 + 193536 + 21504); // 32,256 shorts

    hipFuncSetAttribute(reinterpret_cast<const void*>(net_k),
                        hipFuncAttributeMaxDynamicSharedMemorySize, LDS_BYTES);

    setup_k<<<dim3(231), dim3(256), 0, stream>>>(
        eWf, ebf_, eWi, ebi_, eWc, ebc_, eWo, ebo_,
        dKf, dbf_, dKi, dbi_, dKc, dbc_, dWo, dbo_,
        oK, obv, lW, lb,
        biases, b2, EW, WtA, K2A, flag, prog);

    net_k<<<dim3(256), dim3(512), LDS_BYTES, stream>>>(
        enc_in, dec_in, hPA, hPB, d_out,
        EW, WtA, K2A,
        biases + 0, biases + 96, biases + 192, biases + 288,
        biases + 384, biases + 480, biases + 576, biases + 672,
        b2, flag, prog);
}

// Round 14
// 2159.258 us; speedup vs baseline: 1.2623x; 1.0024x over previous
//
#include <hip/hip_runtime.h>
#include <hip/hip_bf16.h>

#define B_   8
#define T_   12
#define CIN  16
#define HD   96
#define COUT 8
#define CE   112
#define CD   104
#define HW   4096
#define WIMG 64

// LDS layout (bytes):
//   tile  [0, 63360)          4 x 66 x 120 bf16 halo tile
//   cp    [63360, 112512)     c-state  [96 d][128 px] f32  (49,152 B)
//   xp    [112512, 162176)    exchange [128 px][97] f32    (49,664 B)
#define TILE_SHORTS 31680
#define CP_FLOATS   12288
#define LDS_BYTES   162176

typedef __hip_bfloat16 bf16;
typedef __attribute__((ext_vector_type(8))) short bf16x8;   // 8 bf16 (4 VGPRs)
typedef __attribute__((ext_vector_type(16))) float f32x16;  // MFMA 32x32 C/D
typedef __attribute__((ext_vector_type(4))) int i32x4;      // 16B payload

__device__ __forceinline__ float b2f(bf16 v) { return __bfloat162float(v); }
__device__ __forceinline__ float sigmf_(float x) { return 1.0f / (1.0f + __expf(-x)); }
__device__ __forceinline__ float tanhf_(float x) { return 2.0f / (1.0f + __expf(-2.0f * x)) - 1.0f; }

__device__ __forceinline__ float ldin(const void* p, long i, int f32) {
    return f32 ? ((const float*)p)[i] : b2f(((const bf16*)p)[i]);
}
__device__ __forceinline__ short f2bs(float v) {
    __hip_bfloat16 hv = __float2bfloat16(v);
    return *reinterpret_cast<short*>(&hv);
}

// MFMA with "+a": accumulators in AGPRs
__device__ __forceinline__ void mfma_a(f32x16& acc, bf16x8 a, bf16x8 b) {
    asm("v_mfma_f32_32x32x16_bf16 %0, %1, %2, %0"
        : "+a"(acc) : "v"(a), "v"(b));
}

// 16B device-coherent (bypass) loads/stores for cross-block h exchange.
__device__ __forceinline__ i32x4 ldB16(const short* p) {
    i32x4 r;
    asm volatile("global_load_dwordx4 %0, %1, off sc0 sc1"
                 : "=v"(r) : "v"(p) : "memory");
    return r;
}
__device__ __forceinline__ void stB16(short* p, i32x4 v) {
    asm volatile("global_store_dwordx4 %0, %1, off sc0 sc1"
                 :: "v"(p), "v"(v) : "memory");
}
__device__ __forceinline__ void vm0() {
    asm volatile("s_waitcnt vmcnt(0)" ::: "memory");
}

// neighbor-pair progress sync (per-block counter on its own 64B line).
__device__ __forceinline__ void wait_prog(const int* p, int need) {
    while (__hip_atomic_load(p, __ATOMIC_RELAXED, __HIP_MEMORY_SCOPE_AGENT) < need)
        __builtin_amdgcn_s_sleep(1);
}

__device__ __forceinline__ int detect_flag(const void* w) {
    const unsigned short* u = (const unsigned short*)w;
    int bad = 0;
    for (int i = 0; i < 64; i++) {
        unsigned short v = u[i];
        unsigned e = (v >> 7) & 0xFF;
        if (!(v == 0 || (e >= 90 && e <= 128))) bad++;
    }
    return (bad > 8) ? 1 : 0;
}

// ---------------------------------------------------------------------------
// ONE fused setup kernel (unchanged layouts). Block ranges:
//   0-2: biases  3: b2+flag  4: prog zero  5-25: EW  26-214: WtA  215-230: K2A
// ---------------------------------------------------------------------------
__global__ void setup_k(
    const void* eWf, const void* ebf_, const void* eWi, const void* ebi_,
    const void* eWc, const void* ebc_, const void* eWo, const void* ebo_,
    const void* dKf, const void* dbf_, const void* dKi, const void* dbi_,
    const void* dKc, const void* dbc_, const void* dWo, const void* dbo_,
    const void* oK,  const void* obv,  const void* lW,  const void* lb,
    float* __restrict__ biases, float* __restrict__ b2,
    short* __restrict__ EW, short* __restrict__ WtA, short* __restrict__ K2A,
    int* __restrict__ flag, int* __restrict__ prog)
{
    const int f = detect_flag(eWf);
    const int bid = blockIdx.x, tid = threadIdx.x;

    if (bid < 3) {
        int idx = bid * 256 + tid;
        if (idx < 768) {
            const void* srcs[8] = {ebf_, ebi_, ebc_, ebo_, dbf_, dbi_, dbc_, dbo_};
            biases[idx] = ldin(srcs[idx / 96], idx % 96, f);
        }
        return;
    }
    if (bid == 3) {
        if (tid < COUT) {
            float a = ldin(lb, tid, f);
            for (int cd = 0; cd < CD; cd++)
                a = fmaf(ldin(obv, cd, f), ldin(lW, cd * COUT + tid, f), a);
            b2[tid] = a;
        }
        if (tid == 32) *flag = f;
        return;
    }
    if (bid == 4) {
        __hip_atomic_store(&prog[tid * 16], 0, __ATOMIC_RELAXED, __HIP_MEMORY_SCOPE_AGENT);
        return;
    }
    if (bid < 26) {                              // EW
        int lin = (bid - 5) * 256 + tid;
        if (lin >= 7 * 12 * 64) return;
        int lane = lin & 63;
        int rest = lin >> 6;
        int mt = rest % 12;
        int k0 = rest / 12;
        int m = mt * 32 + (lane & 31);
        int gate = m / 96, d = m % 96;
        int chb = k0 * 16 + (lane >> 5) * 8;
        const void* W = (gate == 0) ? eWf : (gate == 1) ? eWi : (gate == 2) ? eWc : eWo;
        #pragma unroll
        for (int j = 0; j < 8; j++)
            EW[(size_t)lin * 8 + j] = f2bs(ldin(W, (size_t)(chb + j) * HD + d, f));
        return;
    }
    if (bid < 215) {                             // WtA
        int lin = (bid - 26) * 256 + tid;
        if (lin >= 9 * 7 * 12 * 64) return;
        int lane = lin & 63;
        int rest = lin >> 6;
        int mt  = rest % 12;
        int k07 = rest / 12;
        int k0  = k07 % 7;
        int tap = k07 / 7;
        int m = mt * 32 + (lane & 31);
        int gate = m / 96, d = m % 96;
        int chb = k0 * 16 + (lane >> 5) * 8;
        #pragma unroll
        for (int j = 0; j < 8; j++) {
            int ch = chb + j;
            float v = 0.f;
            if (ch < 104) {
                long ki = ((long)d * CD + ch) * 9 + tap;
                if (gate == 0)      v = ldin(dKf, ki, f);
                else if (gate == 1) v = ldin(dKi, ki, f);
                else if (gate == 2) v = ldin(dKc, ki, f);
                else                v = (tap == 4) ? ldin(dWo, (long)ch * HD + d, f) : 0.f;
            }
            WtA[(size_t)lin * 8 + j] = f2bs(v);
        }
        return;
    }
    {                                            // K2A with combine inline
        int lin = (bid - 215) * 256 + tid;
        if (lin >= 9 * 7 * 64) return;
        int lane = lin & 63;
        int rest = lin >> 6;
        int k0 = rest % 7;
        int tap = rest / 7;
        int m = lane & 31;
        int kb = k0 * 16 + (lane >> 5) * 8;
        #pragma unroll 1
        for (int j = 0; j < 8; j++) {
            int c = kb + j - 8;
            float v = 0.f;
            if (m < 8 && c >= 0 && c < 96) {
                long i = (long)c * 9 + tap;
                for (int cd = 0; cd < CD; cd++)
                    v = fmaf(ldin(oK, (long)cd * (HD * 9) + i, f),
                             ldin(lW, (long)cd * COUT + m, f), v);
            }
            K2A[(size_t)lin * 8 + j] = f2bs(v);
        }
    }
}

// ---------------------------------------------------------------------------
// persistent kernel, 8-wave M-SPLIT blocks: 512 threads, grid 256 (1/CU).
// Group A (waves 0-3): f,i gate tiles + c-state + h-write, for px 0..127.
// Group B (waves 4-7): g,o gate tiles + out-head, SAME px.
// c-state lives in LDS [96][128] f32 (NOT registers): this removes the
// cre[48] arch-register load that spilled in R11-R13 (VGPR cap 128 at
// 2 waves/SIMD). Gate exchange is ONE f32 plane used twice per step
// (tanh(g) then sigm(o)), with A's c-update / B's out-store between.
// All arithmetic ops and order unchanged -> bit-identical output.
// ---------------------------------------------------------------------------
__global__ void __launch_bounds__(512, 2) net_k(
    const void* __restrict__ xe, const void* __restrict__ xd,
    short* __restrict__ hPA, short* __restrict__ hPB,
    void* __restrict__ out,
    const short* __restrict__ EW, const short* __restrict__ WtA,
    const short* __restrict__ K2A,
    const float* __restrict__ ebf, const float* __restrict__ ebi,
    const float* __restrict__ ebc, const float* __restrict__ ebo,
    const float* __restrict__ dbf, const float* __restrict__ dbi,
    const float* __restrict__ dbc, const float* __restrict__ dbo,
    const float* __restrict__ b2, const int* __restrict__ flag,
    int* __restrict__ prog)
{
    extern __shared__ short lds[];            // 162,176 B dynamic
    float* cp = (float*)(lds + TILE_SHORTS);  // c-state [d][px]
    float* xp = cp + CP_FLOATS;               // exchange [px][97]
    const int f32 = *flag;
    const int tid  = threadIdx.x;
    const int b    = blockIdx.x & 7;
    const int band = blockIdx.x >> 3;         // 0..31
    const int y0   = band * 2;
    const int pix0 = y0 * 64;
    const int wave = tid >> 6, lane = tid & 63;
    const int grp  = wave >> 2;               // 0 = f,i/c-owner  1 = g,o/out
    const int wv   = wave & 3;
    const int n = lane & 31, kj = lane >> 5;
    const int px = wv * 32 + n;               // block-local pixel 0..127
    const int pg = pix0 + px;                 // global pixel
    const i32x4 z4 = {0, 0, 0, 0};

    // zero c-plane (first read happens well after the next barrier)
    #pragma unroll 1
    for (int i = tid; i < CP_FLOATS; i += 512) cp[i] = 0.f;

    // ================= encoder phase =====
    #pragma unroll 1
    for (int t = 0; t < T_; t++) {
        // x staging: 512 items, one per thread
        {
            int ch = tid & 15, q = tid >> 4;
            size_t base = ((size_t)(b * T_ + t) * CIN + ch) * HW + pix0 + q * 4;
            short v0, v1, v2, v3;
            if (f32) {
                float4 f = *(const float4*)((const float*)xe + base);
                v0 = f2bs(f.x); v1 = f2bs(f.y); v2 = f2bs(f.z); v3 = f2bs(f.w);
            } else {
                short4 sv = *(const short4*)((const short*)xe + base);
                v0 = sv.x; v1 = sv.y; v2 = sv.z; v3 = sv.w;
            }
            int sb = q * 4;
            lds[(sb + 0) * 120 + ch] = v0;
            lds[(sb + 1) * 120 + ch] = v1;
            lds[(sb + 2) * 120 + ch] = v2;
            lds[(sb + 3) * 120 + ch] = v3;
        }
        __syncthreads();

        f32x16 acc[6];
        #pragma unroll
        for (int m = 0; m < 6; m++)
            #pragma unroll
            for (int r = 0; r < 16; r++) acc[m][r] = 0.f;

        const short* rec = &lds[px * 120];
        const int mt0 = grp * 6;
        const int k0max = (t == 0) ? 1 : 7;
        #pragma unroll 1
        for (int k0 = 0; k0 < k0max; k0++) {
            bf16x8 bB = *(const bf16x8*)(rec + k0 * 16 + kj * 8);
            #pragma unroll
            for (int m = 0; m < 6; m++)
                mfma_a(acc[m], *(const bf16x8*)(EW + (size_t)(k0 * 12 + mt0 + m) * 512 + lane * 8), bB);
        }
        __syncthreads();

        // B: publish tanh(g)
        if (grp == 1) {
            #pragma unroll
            for (int dt = 0; dt < 3; dt++)
                #pragma unroll
                for (int r = 0; r < 16; r++) {
                    int row = (r & 3) + 8 * (r >> 2) + 4 * kj;
                    int d = dt * 32 + row;
                    xp[px * 97 + d] = tanhf_(acc[dt][r] + ebc[d]);
                }
        }
        __syncthreads();
        // A: c update (c in LDS)
        if (grp == 0) {
            #pragma unroll
            for (int dt = 0; dt < 3; dt++)
                #pragma unroll
                for (int r = 0; r < 16; r++) {
                    int row = (r & 3) + 8 * (r >> 2) + 4 * kj;
                    int d = dt * 32 + row;
                    float fg = sigmf_(acc[dt][r]     + ebf[d]);
                    float ig = sigmf_(acc[3 + dt][r] + ebi[d]);
                    cp[d * 128 + px] = fmaf(cp[d * 128 + px], fg, ig * xp[px * 97 + d]);
                }
        }
        __syncthreads();
        // B: publish sigm(o)  (overwrites plane)
        if (grp == 1) {
            #pragma unroll
            for (int dt = 0; dt < 3; dt++)
                #pragma unroll
                for (int r = 0; r < 16; r++) {
                    int row = (r & 3) + 8 * (r >> 2) + 4 * kj;
                    int d = dt * 32 + row;
                    xp[px * 97 + d] = sigmf_(acc[3 + dt][r] + ebo[d]);
                }
        }
        __syncthreads();
        // A: h = tanh(c) * o -> tile
        if (grp == 0) {
            #pragma unroll
            for (int dt = 0; dt < 3; dt++)
                #pragma unroll
                for (int r = 0; r < 16; r++) {
                    int row = (r & 3) + 8 * (r >> 2) + 4 * kj;
                    int d = dt * 32 + row;
                    lds[px * 120 + 16 + d] = f2bs(tanhf_(cp[d * 128 + px]) * xp[px * 97 + d]);
                }
        }
        __syncthreads();
        if (t == T_ - 1) {
            // publish final enc h: 128 recs x 12 parts x 16B = full 96 ch
            #pragma unroll 1
            for (int c = tid; c < 1536; c += 512) {
                int rec2 = c / 12, part = c - (c / 12) * 12;
                stB16(hPA + ((size_t)b * HW + pix0 + rec2) * 96 + part * 8,
                      *(const i32x4*)(&lds[rec2 * 120 + 16 + part * 8]));
            }
        }
    }
    vm0();
    __syncthreads();
    if (tid == 0)
        __hip_atomic_store(&prog[blockIdx.x * 16], 1, __ATOMIC_RELAXED, __HIP_MEMORY_SCOPE_AGENT);

    // ================= decoder phase =====
    #pragma unroll 1
    for (int tt = 0; tt <= T_; tt++) {
        short* hR  = (tt & 1) ? hPB : hPA;    // h_{tt-1}
        short* hWr = (tt & 1) ? hPA : hPB;    // h_tt

        if (tt == 0) {
            // zero pass: edge slots + ch pads
            #pragma unroll 1
            for (int i = tid; i < 648; i += 512) {
                int addr_sh;
                if (i < 120) {
                    int r = i / 30, rem = i % 30;
                    int s = (rem / 15) * 65;
                    addr_sh = (r * 66 + s) * 120 + (rem % 15) * 8;
                } else {
                    int z = i - 120;
                    addr_sh = (z >> 1) * 120 + 104 + (z & 1) * 8;
                }
                *(i32x4*)(&lds[addr_sh]) = z4;
            }
        }
        // x staging: 512 items (skip on final out-only pass)
        if (tt < T_) {
            int ch = tid & 7, q = (tid >> 3) & 15, r = tid >> 7;
            int y = y0 - 1 + r;
            short v0 = 0, v1 = 0, v2 = 0, v3 = 0;
            if ((unsigned)y < 64u) {
                size_t base = ((size_t)(b * T_ + tt) * COUT + ch) * HW + y * 64 + q * 4;
                if (f32) {
                    float4 f = *(const float4*)((const float*)xd + base);
                    v0 = f2bs(f.x); v1 = f2bs(f.y); v2 = f2bs(f.z); v3 = f2bs(f.w);
                } else {
                    short4 sv = *(const short4*)((const short*)xd + base);
                    v0 = sv.x; v1 = sv.y; v2 = sv.z; v3 = sv.w;
                }
            }
            int sb = r * 66 + 1 + q * 4;
            lds[(sb + 0) * 120 + ch] = v0;
            lds[(sb + 1) * 120 + ch] = v1;
            lds[(sb + 2) * 120 + ch] = v2;
            lds[(sb + 3) * 120 + ch] = v3;
        }

        // neighbor sync: need h_{tt-1} of bands band+-1 published (prog>=tt+1)
        if (tid < 2) {
            int nb = band + (tid ? 1 : -1);
            if ((unsigned)nb < 32u)
                wait_prog(prog + (((nb << 3) | b) << 4), tt + 1);
        }
        __syncthreads();

        if (tt == 0) {
            // full h staging: 3072 chunks, 6 per thread
            i32x4 tmp[6]; int ss2[6], jj2[6];
            #pragma unroll
            for (int i = 0; i < 6; i++) {
                int c2 = tid + i * 512;
                int s = c2 / 12, j = c2 - s * 12;
                ss2[i] = s; jj2[i] = j;
                int y = y0 - 1 + (s >> 6);
                if ((unsigned)y < 64u)
                    tmp[i] = ldB16(hR + ((size_t)b * HW + (size_t)y * 64 + (s & 63)) * 96 + j * 8);
                else tmp[i] = z4;
            }
            vm0();
            #pragma unroll
            for (int i = 0; i < 6; i++) {
                int s = ss2[i];
                *(i32x4*)(&lds[((s >> 6) * 66 + 1 + (s & 63)) * 120 + 8 + jj2[i] * 8]) = tmp[i];
            }
        } else {
            // halo staging: rows y0-1 (slot 0) and y0+2 (slot 3); 3 per thread
            i32x4 tmp[3]; int ss2[3], jj2[3];
            #pragma unroll
            for (int i = 0; i < 3; i++) {
                int c2 = tid + i * 512;           // 0..1535
                int s = c2 / 12, j = c2 - s * 12; // s 0..127
                int hi = s >> 6;
                int y = hi ? (y0 + 2) : (y0 - 1);
                ss2[i] = hi * 3 * 66 + 1 + (s & 63);
                jj2[i] = j;
                if ((unsigned)y < 64u)
                    tmp[i] = ldB16(hR + ((size_t)b * HW + (size_t)y * 64 + (s & 63)) * 96 + j * 8);
                else tmp[i] = z4;
            }
            vm0();
            #pragma unroll
            for (int i = 0; i < 3; i++)
                *(i32x4*)(&lds[ss2[i] * 120 + 8 + jj2[i] * 8]) = tmp[i];
        }
        __syncthreads();

        const int rw = 1 + (wv >> 1);
        const int x0 = (wv & 1) * 32;

        // UNIONED accumulators: grp0 f=A[0..2],i=A[3..5] (A[6] dead there);
        // grp1 g=A[0..2], o=A[3..5], out=A[6].
        f32x16 A[7];
        #pragma unroll
        for (int m = 0; m < 6; m++)
            #pragma unroll
            for (int r = 0; r < 16; r++) A[m][r] = 0.f;

        // ---- MFMA phase (no barriers inside; groups diverge at wave level)
        if (grp == 0 && tt < T_) {
            // f,i tiles (mt 0-5), u = tap*7+k0 ascending (same acc order)
            #pragma unroll 1
            for (int u = 0; u < 63; u++) {
                int tap = u / 7, k0 = u - tap * 7;
                int dy = tap / 3 - 1, dx = tap - (tap / 3) * 3 - 1;
                bf16x8 bB = *(const bf16x8*)(&lds[((rw + dy) * 66 + 1 + x0 + n + dx) * 120]
                                             + k0 * 16 + kj * 8);
                #pragma unroll
                for (int m = 0; m < 6; m++)
                    mfma_a(A[m], *(const bf16x8*)(WtA + ((size_t)u * 12 + m) * 512 + lane * 8), bB);
            }
        }
        if (grp == 1) {
            #pragma unroll
            for (int r = 0; r < 16; r++) A[6][r] = 0.f;
            // g tiles (mt 6-8) -> A[0..2], out head -> A[6]
            #pragma unroll 1
            for (int u = 0; u < 63; u++) {
                int tap = u / 7, k0 = u - tap * 7;
                int dy = tap / 3 - 1, dx = tap - (tap / 3) * 3 - 1;
                bf16x8 bB = *(const bf16x8*)(&lds[((rw + dy) * 66 + 1 + x0 + n + dx) * 120]
                                             + k0 * 16 + kj * 8);
                if (tt < T_) {
                    #pragma unroll
                    for (int m = 0; m < 3; m++)
                        mfma_a(A[m], *(const bf16x8*)(WtA + ((size_t)u * 12 + 6 + m) * 512 + lane * 8), bB);
                }
                if (tt > 0)
                    mfma_a(A[6], *(const bf16x8*)(K2A + (size_t)u * 512 + lane * 8), bB);
            }
            // o tiles (mt 9-11) -> A[3..5]: center tap only (u = 28..34)
            if (tt < T_) {
                const short* recc = &lds[(rw * 66 + 1 + x0 + n) * 120];
                #pragma unroll 1
                for (int k0 = 0; k0 < 7; k0++) {
                    bf16x8 bB2 = *(const bf16x8*)(recc + k0 * 16 + kj * 8);
                    #pragma unroll
                    for (int m = 0; m < 3; m++)
                        mfma_a(A[3 + m], *(const bf16x8*)(WtA + ((size_t)(28 + k0) * 12 + 9 + m) * 512 + lane * 8), bB2);
                }
            }
        }
        __syncthreads();

        // B: publish tanh(g)
        if (grp == 1 && tt < T_) {
            #pragma unroll
            for (int dt = 0; dt < 3; dt++)
                #pragma unroll
                for (int r = 0; r < 16; r++) {
                    int row = (r & 3) + 8 * (r >> 2) + 4 * kj;
                    int d = dt * 32 + row;
                    xp[px * 97 + d] = tanhf_(A[dt][r] + dbc[d]);
                }
        }
        __syncthreads();

        // A: c update || B: out store for step tt-1 (A[6])
        if (grp == 1 && tt > 0) {
            #pragma unroll
            for (int r = 0; r < 4; r++) {
                int o = r + 4 * kj;
                float v = A[6][r] + b2[o];
                size_t oadr = ((size_t)(b * T_ + (tt - 1)) * COUT + o) * HW + pg;
                if (f32) ((float*)out)[oadr] = v;
                else     ((bf16*)out)[oadr] = __float2bfloat16(v);
            }
        }
        if (grp == 0 && tt < T_) {
            #pragma unroll
            for (int dt = 0; dt < 3; dt++)
                #pragma unroll
                for (int r = 0; r < 16; r++) {
                    int row = (r & 3) + 8 * (r >> 2) + 4 * kj;
                    int d = dt * 32 + row;
                    float fg = sigmf_(A[dt][r]     + dbf[d]);
                    float ig = sigmf_(A[3 + dt][r] + dbi[d]);
                    cp[d * 128 + px] = fmaf(cp[d * 128 + px], fg, ig * xp[px * 97 + d]);
                }
        }
        __syncthreads();

        // B: publish sigm(o)
        if (grp == 1 && tt < T_) {
            #pragma unroll
            for (int dt = 0; dt < 3; dt++)
                #pragma unroll
                for (int r = 0; r < 16; r++) {
                    int row = (r & 3) + 8 * (r >> 2) + 4 * kj;
                    int d = dt * 32 + row;
                    xp[px * 97 + d] = sigmf_(A[3 + dt][r] + dbo[d]);
                }
        }
        __syncthreads();

        // A: h = tanh(c) * o -> staged rows
        if (grp == 0 && tt < T_) {
            #pragma unroll
            for (int dt = 0; dt < 3; dt++)
                #pragma unroll
                for (int r = 0; r < 16; r++) {
                    int row = (r & 3) + 8 * (r >> 2) + 4 * kj;
                    int d = dt * 32 + row;
                    lds[((1 + (px >> 6)) * 66 + 1 + (px & 63)) * 120 + 8 + d]
                        = f2bs(tanhf_(cp[d * 128 + px]) * xp[px * 97 + d]);
                }
        }
        __syncthreads();

        if (tt < T_) {
            // publish own 2 rows: 128 recs x 12 parts x 16B = full 96 ch
            #pragma unroll 1
            for (int c = tid; c < 1536; c += 512) {
                int rec2 = c / 12, part = c - (c / 12) * 12;
                stB16(hWr + ((size_t)b * HW + pix0 + rec2) * 96 + part * 8,
                      *(const i32x4*)(&lds[((1 + (rec2 >> 6)) * 66 + 1 + (rec2 & 63)) * 120
                                           + 8 + part * 8]));
            }
            vm0();
            __syncthreads();
            if (tid == 0)
                __hip_atomic_store(&prog[blockIdx.x * 16], tt + 2,
                                   __ATOMIC_RELAXED, __HIP_MEMORY_SCOPE_AGENT);
        }
    }
}

// ---------------------------------------------------------------------------
extern "C" void kernel_launch(void* const* d_in, const int* in_sizes, int n_in,
                              void* d_out, int out_size, void* d_ws, size_t ws_size,
                              hipStream_t stream)
{
    const void* enc_in = d_in[0];
    const void* dec_in = d_in[1];
    const void* eWf = d_in[2];  const void* ebf_ = d_in[3];
    const void* eWi = d_in[4];  const void* ebi_ = d_in[5];
    const void* eWc = d_in[6];  const void* ebc_ = d_in[7];
    const void* eWo = d_in[8];  const void* ebo_ = d_in[9];
    const void* dKf = d_in[10]; const void* dbf_ = d_in[11];
    const void* dKi = d_in[12]; const void* dbi_ = d_in[13];
    const void* dKc = d_in[14]; const void* dbc_ = d_in[15];
    const void* dWo = d_in[16]; const void* dbo_ = d_in[17];
    const void* oK  = d_in[18]; const void* obv = d_in[19];
    const void* lW  = d_in[20]; const void* lb  = d_in[21];

    int* flag = (int*)d_ws;
    int* prog = (int*)d_ws + 16;             // 256 slots x 16 ints (64B stride)
    float* ws = (float*)d_ws + 16 + 4096;

    const int S = B_ * HD * HW;              // 3,145,728 state elems
    short* hPA = (short*)ws;                 // S shorts (pixel-major h)
    short* hPB = (short*)(ws + S / 2);       // S shorts
    float* biases = ws + S;                  // 8 x 96 fp32
    float* b2   = biases + 768;              // 16
    short* WtA  = (short*)(b2 + 16);                  // 387,072 shorts
    short* EW   = (short*)(b2 + 16 + 193536);         // 43,008 shorts
    short* K2A  = (short*)(b2 + 16 + 193536 + 21504); // 32,256 shorts

    hipFuncSetAttribute(reinterpret_cast<const void*>(net_k),
                        hipFuncAttributeMaxDynamicSharedMemorySize, LDS_BYTES);

    setup_k<<<dim3(231), dim3(256), 0, stream>>>(
        eWf, ebf_, eWi, ebi_, eWc, ebc_, eWo, ebo_,
        dKf, dbf_, dKi, dbi_, dKc, dbc_, dWo, dbo_,
        oK, obv, lW, lb,
        biases, b2, EW, WtA, K2A, flag, prog);

    net_k<<<dim3(256), dim3(512), LDS_BYTES, stream>>>(
        enc_in, dec_in, hPA, hPB, d_out,
        EW, WtA, K2A,
        biases + 0, biases + 96, biases + 192, biases + 288,
        biases + 384, biases + 480, biases + 576, biases + 672,
        b2, flag, prog);
}